// Round 2
// baseline (1682.003 us; speedup 1.0000x reference)
//
#include <hip/hip_runtime.h>
#include <stdint.h>
#include <math.h>

#define NS 32   // nsample
// S = 4, oc = 32 for layers 1..7 (5*oc = 160 fout cols), layer 8: oc=1024 (5120 cols)

// ---------------- threefry2x32 (exact JAX semantics) ----------------
__device__ __forceinline__ void threefry(uint32_t k0, uint32_t k1,
                                         uint32_t x0, uint32_t x1,
                                         uint32_t& o0, uint32_t& o1)
{
    uint32_t ks0 = k0, ks1 = k1, ks2 = k0 ^ k1 ^ 0x1BD11BDAu;
    x0 += ks0; x1 += ks1;
    const int rotA[4] = {13, 15, 26, 6};
    const int rotB[4] = {17, 29, 16, 24};
    uint32_t ks[3] = {ks0, ks1, ks2};
#pragma unroll
    for (int i = 0; i < 5; ++i) {
        const int* r = (i & 1) ? rotB : rotA;
#pragma unroll
        for (int j = 0; j < 4; ++j) {
            x0 += x1;
            x1 = (x1 << r[j]) | (x1 >> (32 - r[j]));
            x1 ^= x0;
        }
        x0 += ks[(i + 1) % 3];
        x1 += ks[(i + 2) % 3] + (uint32_t)(i + 1);
    }
    o0 = x0; o1 = x1;
}

// PARTITIONABLE-mode keys for round `round` of jax _shuffle(key(seed), arange(n)).
// jax>=0.4.30 defaults jax_threefry_partitionable=True:
//   split(key)  : key' = TF(key,(0,0)), subkey = TF(key,(0,1))   (fold_in-based)
//   bits32[i]   : o0 ^ o1 of TF(subkey,(hi=0, lo=i))             (64-bit counter)
__global__ void perm_genkeys(uint32_t* __restrict__ keys, int* __restrict__ val,
                             uint32_t seed, int round, int n, int initval)
{
    int i = blockIdx.x * blockDim.x + threadIdx.x;
    if (i >= n) return;
    uint32_t k0 = 0u, k1 = seed;
    for (int r = 0; r < round; ++r) {           // advance key chain: key = TF(key,(0,0))
        uint32_t a0, a1;
        threefry(k0, k1, 0u, 0u, a0, a1);
        k0 = a0; k1 = a1;
    }
    uint32_t s0, s1;
    threefry(k0, k1, 0u, 1u, s0, s1);           // subkey = TF(key,(0,1))
    uint32_t y0, y1;
    threefry(s0, s1, 0u, (uint32_t)i, y0, y1);  // counter hi=0, lo=i
    keys[i] = y0 ^ y1;                          // 32-bit fold of the two output words
    if (initval) val[i] = i;
}

// stable ascending rank-scatter: vout[rank(i)] = vin[i]
template <int N>
__global__ void perm_rank(const uint32_t* __restrict__ keys,
                          const int* __restrict__ vin, int* __restrict__ vout)
{
    __shared__ uint32_t sk[N];
    for (int j = threadIdx.x; j < N; j += blockDim.x) sk[j] = keys[j];
    __syncthreads();
    int i = blockIdx.x * blockDim.x + threadIdx.x;
    if (i >= N) return;
    uint32_t k = sk[i];
    int rank = 0;
    for (int j = 0; j < N; ++j) {
        uint32_t kj = sk[j];
        rank += (int)((kj < k) | ((kj == k) & (j < i)));
    }
    vout[rank] = vin[i];
}

// ---------------- query_ball_point + neighbor directions ----------------
template <int MAXV>
__global__ void qbp_kernel(const float* __restrict__ pts, int Vv, float r2,
                           int* __restrict__ idx, float* __restrict__ nd)
{
#pragma clang fp contract(off)
    __shared__ float sx[MAXV], sy[MAXV], sz[MAXV];
    int b = blockIdx.y;
    const float* P = pts + (size_t)b * Vv * 3;
    for (int j = threadIdx.x; j < Vv; j += blockDim.x) {
        sx[j] = P[j * 3 + 0]; sy[j] = P[j * 3 + 1]; sz[j] = P[j * 3 + 2];
    }
    __syncthreads();
    int v = blockIdx.x * blockDim.x + threadIdx.x;
    if (v >= Vv) return;
    float qx = sx[v], qy = sy[v], qz = sz[v];
    float aa = (qx * qx + qy * qy) + qz * qz;
    int* orow = idx + ((size_t)b * Vv + v) * NS;
    float* nrow = nd + ((size_t)b * Vv + v) * NS * 3;
    int cnt = 0;
    for (int j = 0; j < Vv; ++j) {
        float px = sx[j], py = sy[j], pz = sz[j];
        float bb2 = (px * px + py * py) + pz * pz;
        float dot = (qx * px + qy * py) + qz * pz;
        float d2 = (aa + bb2) - 2.0f * dot;            // matches aa+bb-2*einsum
        if (d2 <= r2) {                                // reference masks d2 > r^2
            float dx = px - qx, dy = py - qy, dz = pz - qz;
            float nn = sqrtf((dx * dx + dy * dy) + dz * dz);
            float mm = fmaxf(nn, 1e-12f);
            orow[cnt] = j;
            nrow[cnt * 3 + 0] = dx / mm;
            nrow[cnt * 3 + 1] = dy / mm;
            nrow[cnt * 3 + 2] = dz / mm;
            ++cnt;
            if (cnt == NS) break;
        }
    }
    int f0 = orow[0];                                   // self always valid -> cnt>=1
    float n0 = nrow[0], n1 = nrow[1], n2 = nrow[2];
    for (int k = cnt; k < NS; ++k) {
        orow[k] = f0;
        nrow[k * 3 + 0] = n0; nrow[k * 3 + 1] = n1; nrow[k * 3 + 2] = n2;
    }
}

// ---------------- conv_surface (oc=32, K=S*32=128) ----------------
__global__ void conv_surface_kernel(const float* __restrict__ nd, const float* __restrict__ dirs,
                                    float* __restrict__ fm, int Vv, int Cstr, int coff)
{
    __shared__ float snd[NS * 3];
    __shared__ float sm[128];
    int b = blockIdx.y, v = blockIdx.x, t = threadIdx.x;
    size_t row = (size_t)b * Vv + v;
    if (t < NS * 3) snd[t] = nd[row * NS * 3 + t];
    __syncthreads();
    float w0 = dirs[t], w1 = dirs[128 + t], w2 = dirs[256 + t];
    float nn = sqrtf(w0 * w0 + w1 * w1 + w2 * w2);
    float mm = fmaxf(nn, 1e-12f);
    w0 /= mm; w1 /= mm; w2 /= mm;
    float mx = -INFINITY;
#pragma unroll
    for (int n = 0; n < NS; ++n) {
        float th = fmaxf(snd[n * 3] * w0 + snd[n * 3 + 1] * w1 + snd[n * 3 + 2] * w2, 0.0f);
        mx = fmaxf(mx, th);
    }
    sm[t] = mx;
    __syncthreads();
    if (t < 32) {
        float o = ((sm[t] + sm[32 + t]) + sm[64 + t]) + sm[96 + t];  // sum over S
        o = fmaxf(o, 0.0f);                                          // outer relu
        fm[row * Cstr + coff + t] = o;
    }
}

// ---------------- fout = fm[:, :ic] @ W + b  (cols = 160) ----------------
__global__ void fout_kernel(const float* __restrict__ fm, const float* __restrict__ W,
                            const float* __restrict__ bias, float* __restrict__ fout,
                            int rows, int ic, int Cstr)
{
    int tid = blockIdx.x * blockDim.x + threadIdx.x;
    if (tid >= rows * 160) return;
    int row = tid / 160, col = tid - row * 160;
    const float* fr = fm + (size_t)row * Cstr;
    float acc = 0.f;
    for (int i = 0; i < ic; ++i) acc += fr[i] * W[i * 160 + col];
    fout[(size_t)row * 160 + col] = acc + bias[col];
}

// ---------------- conv_layer act (oc=32): center + max_n(theta*support) summed over S ----
__global__ void act32_kernel(const float* __restrict__ nd, const int* __restrict__ idx,
                             const float* __restrict__ fout, const float* __restrict__ dirs,
                             float* __restrict__ fm, int Vv, int Cstr, int coff, int dorelu)
{
    __shared__ float snd[NS * 3];
    __shared__ int sidx[NS];
    __shared__ float sm[128];
    int b = blockIdx.y, v = blockIdx.x, t = threadIdx.x;
    size_t row = (size_t)b * Vv + v;
    if (t < NS * 3) snd[t] = nd[row * NS * 3 + t];
    if (t < NS) sidx[t] = idx[row * NS + t];
    __syncthreads();
    float w0 = dirs[t], w1 = dirs[128 + t], w2 = dirs[256 + t];
    float nn = sqrtf(w0 * w0 + w1 * w1 + w2 * w2);
    float mm = fmaxf(nn, 1e-12f);
    w0 /= mm; w1 /= mm; w2 /= mm;
    float mx = -INFINITY;
    for (int n = 0; n < NS; ++n) {
        float th = fmaxf(snd[n * 3] * w0 + snd[n * 3 + 1] * w1 + snd[n * 3 + 2] * w2, 0.0f);
        float sup = fout[((size_t)b * Vv + sidx[n]) * 160 + 32 + t];
        mx = fmaxf(mx, th * sup);
    }
    sm[t] = mx;
    __syncthreads();
    if (t < 32) {
        float act = ((sm[t] + sm[32 + t]) + sm[64 + t]) + sm[96 + t];
        float o = fout[row * 160 + t] + act;           // center + act
        if (dorelu) o = fmaxf(o, 0.0f);
        fm[row * Cstr + coff + t] = o;
    }
}

// ---------------- pool: gather-max over first 4 neighbors at permuted rows ----------------
__global__ void pool_kernel(const float* __restrict__ fmin, const int* __restrict__ idxp,
                            const int* __restrict__ perm, const float* __restrict__ vin,
                            float* __restrict__ fmout, float* __restrict__ vout,
                            int Vin, int Vout, int Cin, int Cout)
{
    int b = blockIdx.y, nv = blockIdx.x, t = threadIdx.x;
    int pv = perm[nv];
    size_t inrow = (size_t)b * Vin + pv;
    const int* ir = idxp + inrow * NS;   // radius/pointset identical -> first 4 of 32-idx
    int j0 = ir[0], j1 = ir[1], j2 = ir[2], j3 = ir[3];
    if (t < Cin) {
        const float* base = fmin + (size_t)b * Vin * Cin;
        float m = base[(size_t)j0 * Cin + t];
        m = fmaxf(m, base[(size_t)j1 * Cin + t]);
        m = fmaxf(m, base[(size_t)j2 * Cin + t]);
        m = fmaxf(m, base[(size_t)j3 * Cin + t]);
        fmout[((size_t)b * Vout + nv) * Cout + t] = m;
    }
    if (t == 0) {
        vout[((size_t)b * Vout + nv) * 3 + 0] = vin[inrow * 3 + 0];
        vout[((size_t)b * Vout + nv) * 3 + 1] = vin[inrow * 3 + 1];
        vout[((size_t)b * Vout + nv) * 3 + 2] = vin[inrow * 3 + 2];
    }
}

// ---------------- layer-8 GEMM: (512 x 256) @ (256 x 5120) + b ----------------
__global__ void fout8_kernel(const float* __restrict__ fm, const float* __restrict__ W,
                             const float* __restrict__ bias, float* __restrict__ out)
{
    __shared__ float sA[16 * 256];   // 16 rows x full K
    __shared__ float sB[32 * 256];   // 32 k x 256 cols
    int ct = blockIdx.x, rt = blockIdx.y, t = threadIdx.x;
    int row0 = rt * 16, col0 = ct * 256;
    for (int i = t; i < 16 * 256; i += 256) {
        int r = i >> 8, k = i & 255;
        sA[i] = fm[(size_t)(row0 + r) * 256 + k];
    }
    float acc[16];
#pragma unroll
    for (int r = 0; r < 16; ++r) acc[r] = 0.f;
    for (int kt = 0; kt < 256; kt += 32) {
        __syncthreads();
        for (int i = t; i < 32 * 256; i += 256) {
            int k = i >> 8, c = i & 255;
            sB[i] = W[(size_t)(kt + k) * 5120 + col0 + c];
        }
        __syncthreads();
#pragma unroll 8
        for (int k = 0; k < 32; ++k) {
            float bv = sB[k * 256 + t];
#pragma unroll
            for (int r = 0; r < 16; ++r) acc[r] += sA[r * 256 + kt + k] * bv;
        }
    }
    float bb = bias[col0 + t];
#pragma unroll
    for (int r = 0; r < 16; ++r)
        out[(size_t)(row0 + r) * 5120 + col0 + t] = acc[r] + bb;
}

// ---------------- layer-8 act (oc=1024, K=S*1024=4096) ----------------
__global__ void act8_kernel(const float* __restrict__ nd, const int* __restrict__ idx,
                            const float* __restrict__ fout8, const float* __restrict__ dir8,
                            float* __restrict__ fm8)
{
    __shared__ float sdx[4096], sdy[4096], sdz[4096];   // 48 KB normalized dirs
    __shared__ float snd[NS * 3];
    __shared__ int sidx[NS];
    int b = blockIdx.y, v = blockIdx.x, t = threadIdx.x;
    for (int c = t; c < 4096; c += 256) {
        float w0 = dir8[c], w1 = dir8[4096 + c], w2 = dir8[8192 + c];
        float nn = sqrtf(w0 * w0 + w1 * w1 + w2 * w2);
        float mm = fmaxf(nn, 1e-12f);
        sdx[c] = w0 / mm; sdy[c] = w1 / mm; sdz[c] = w2 / mm;
    }
    size_t row = (size_t)b * 256 + v;
    if (t < NS * 3) snd[t] = nd[row * NS * 3 + t];
    if (t < NS) sidx[t] = idx[row * NS + t];
    __syncthreads();
    float mx[16];
#pragma unroll
    for (int u = 0; u < 16; ++u) mx[u] = -INFINITY;
    for (int n = 0; n < NS; ++n) {
        float a0 = snd[n * 3], a1 = snd[n * 3 + 1], a2 = snd[n * 3 + 2];
        const float* sup = fout8 + ((size_t)b * 256 + sidx[n]) * 5120 + 1024;
#pragma unroll
        for (int u = 0; u < 16; ++u) {
            int k = t + 256 * u;
            float th = fmaxf(a0 * sdx[k] + a1 * sdy[k] + a2 * sdz[k], 0.0f);
            mx[u] = fmaxf(mx[u], th * sup[k]);
        }
    }
    // k = t + 256u -> s = u>>2, c = t + 256*(u&3): S-reduction is thread-local
    const float* crow = fout8 + row * 5120;
#pragma unroll
    for (int w = 0; w < 4; ++w) {
        int c = t + 256 * w;
        float act = ((mx[w] + mx[4 + w]) + mx[8 + w]) + mx[12 + w];
        fm8[row * 1024 + c] = crow[c] + act;            // no relu on fm8
    }
}

// ---------------- global max over vertices ----------------
__global__ void gmax_kernel(const float* __restrict__ fm8, float* __restrict__ gfeat)
{
    int t = blockIdx.x * blockDim.x + threadIdx.x;  // 0..2047
    if (t >= 2048) return;
    int b = t >> 10, c = t & 1023;
    float m = -INFINITY;
    for (int v = 0; v < 256; ++v) m = fmaxf(m, fm8[((size_t)b * 256 + v) * 1024 + c]);
    gfeat[t] = m;
}

// ---------------- classifier head ----------------
__global__ void head_kernel(const float* __restrict__ gfeat,
                            const float* __restrict__ cw1, const float* __restrict__ cb1,
                            const float* __restrict__ bg, const float* __restrict__ bbv,
                            const float* __restrict__ cw2, const float* __restrict__ cb2,
                            float* __restrict__ out)
{
    __shared__ float sg[1024];
    __shared__ float sh[256];
    int b = blockIdx.x, t = threadIdx.x;
    for (int i = t; i < 1024; i += 256) sg[i] = gfeat[b * 1024 + i];
    __syncthreads();
    float acc = 0.f;
    for (int i = 0; i < 1024; ++i) acc += sg[i] * cw1[i * 256 + t];
    float h = acc + cb1[t];
    const float s = sqrtf((float)(1.0 + 1e-5));
    h = h / s * bg[t] + bbv[t];
    h = fmaxf(h, 0.0f);
    sh[t] = h;
    __syncthreads();
    if (t < 40) {
        float a = 0.f;
        for (int i = 0; i < 256; ++i) a += sh[i] * cw2[i * 40 + t];
        out[b * 40 + t] = a + cb2[t];
    }
}

// ==================================================================
extern "C" void kernel_launch(void* const* d_in, const int* in_sizes, int n_in,
                              void* d_out, int out_size, void* d_ws, size_t ws_size,
                              hipStream_t stream)
{
    (void)in_sizes; (void)n_in; (void)out_size; (void)ws_size;
    const float* vertices = (const float*)d_in[0];
    const float* d0 = (const float*)d_in[1];
    const float *w[9], *bw[9], *dir[9];
    for (int i = 1; i <= 8; ++i) {
        w[i]   = (const float*)d_in[2 + (i - 1) * 3];
        bw[i]  = (const float*)d_in[3 + (i - 1) * 3];
        dir[i] = (const float*)d_in[4 + (i - 1) * 3];
    }
    const float* cw1 = (const float*)d_in[26];
    const float* cb1 = (const float*)d_in[27];
    const float* bg  = (const float*)d_in[28];
    const float* bbv = (const float*)d_in[29];
    const float* cw2 = (const float*)d_in[30];
    const float* cb2 = (const float*)d_in[31];
    float* out = (float*)d_out;

    char* ws = (char*)d_ws;
    size_t off = 0;
    auto take = [&](size_t bytes) -> char* {
        char* p = ws + off;
        off = (off + bytes + 255) & ~(size_t)255;
        return p;
    };
    uint32_t* keys1 = (uint32_t*)take(4096 * 4);
    int* valA = (int*)take(4096 * 4);
    int* valB = (int*)take(4096 * 4);
    uint32_t* keys2 = (uint32_t*)take(1024 * 4);
    int* v2A = (int*)take(1024 * 4);
    int* v2B = (int*)take(1024 * 4);
    int*   idx1 = (int*)take((size_t)2 * 4096 * NS * 4);
    float* nd1  = (float*)take((size_t)2 * 4096 * NS * 3 * 4);
    float* fmA  = (float*)take((size_t)2 * 4096 * 96 * 4);
    float* vtxB = (float*)take((size_t)2 * 1024 * 3 * 4);
    int*   idx2 = (int*)take((size_t)2 * 1024 * NS * 4);
    float* nd2  = (float*)take((size_t)2 * 1024 * NS * 3 * 4);
    float* fmB  = (float*)take((size_t)2 * 1024 * 192 * 4);
    float* vtxC = (float*)take((size_t)2 * 256 * 3 * 4);
    int*   idx3 = (int*)take((size_t)2 * 256 * NS * 4);
    float* nd3  = (float*)take((size_t)2 * 256 * NS * 3 * 4);
    float* fmC  = (float*)take((size_t)2 * 256 * 256 * 4);
    float* fm8  = (float*)take((size_t)2 * 256 * 1024 * 4);
    float* gfeat = (float*)take(2 * 1024 * 4);
    float* fout = (float*)take((size_t)512 * 5120 * 4);  // shared by all fout layers

    // permutations (jax.random.permutation, partitionable threefry;
    // 2 sort rounds for n=4096, 1 for n=1024)
    perm_genkeys<<<16, 256, 0, stream>>>(keys1, valA, 1u, 0, 4096, 1);
    perm_rank<4096><<<16, 256, 0, stream>>>(keys1, valA, valB);
    perm_genkeys<<<16, 256, 0, stream>>>(keys1, valA, 1u, 1, 4096, 0);
    perm_rank<4096><<<16, 256, 0, stream>>>(keys1, valB, valA);   // perm1 = valA[:1024]
    perm_genkeys<<<4, 256, 0, stream>>>(keys2, v2A, 2u, 0, 1024, 1);
    perm_rank<1024><<<4, 256, 0, stream>>>(keys2, v2A, v2B);      // perm2 = v2B[:256]

    const float r2a = (float)(0.2 * 0.2), r2b = (float)(0.4 * 0.4), r2c = (float)(0.6 * 0.6);

    // ---- stage 1: V=4096 ----
    qbp_kernel<4096><<<dim3(16, 2), 256, 0, stream>>>(vertices, 4096, r2a, idx1, nd1);
    conv_surface_kernel<<<dim3(4096, 2), 128, 0, stream>>>(nd1, d0, fmA, 4096, 96, 0);
    fout_kernel<<<(8192 * 160 + 255) / 256, 256, 0, stream>>>(fmA, w[1], bw[1], fout, 8192, 32, 96);
    act32_kernel<<<dim3(4096, 2), 128, 0, stream>>>(nd1, idx1, fout, dir[1], fmA, 4096, 96, 32, 1);
    fout_kernel<<<(8192 * 160 + 255) / 256, 256, 0, stream>>>(fmA, w[2], bw[2], fout, 8192, 64, 96);
    act32_kernel<<<dim3(4096, 2), 128, 0, stream>>>(nd1, idx1, fout, dir[2], fmA, 4096, 96, 64, 1);
    pool_kernel<<<dim3(1024, 2), 128, 0, stream>>>(fmA, idx1, valA, vertices, fmB, vtxB, 4096, 1024, 96, 192);

    // ---- stage 2: V=1024 ----
    qbp_kernel<1024><<<dim3(4, 2), 256, 0, stream>>>(vtxB, 1024, r2b, idx2, nd2);
    fout_kernel<<<(2048 * 160 + 255) / 256, 256, 0, stream>>>(fmB, w[3], bw[3], fout, 2048, 96, 192);
    act32_kernel<<<dim3(1024, 2), 128, 0, stream>>>(nd2, idx2, fout, dir[3], fmB, 1024, 192, 96, 1);
    fout_kernel<<<(2048 * 160 + 255) / 256, 256, 0, stream>>>(fmB, w[4], bw[4], fout, 2048, 128, 192);
    act32_kernel<<<dim3(1024, 2), 128, 0, stream>>>(nd2, idx2, fout, dir[4], fmB, 1024, 192, 128, 1);
    fout_kernel<<<(2048 * 160 + 255) / 256, 256, 0, stream>>>(fmB, w[5], bw[5], fout, 2048, 160, 192);
    act32_kernel<<<dim3(1024, 2), 128, 0, stream>>>(nd2, idx2, fout, dir[5], fmB, 1024, 192, 160, 1);
    pool_kernel<<<dim3(256, 2), 256, 0, stream>>>(fmB, idx2, v2B, vtxB, fmC, vtxC, 1024, 256, 192, 256);

    // ---- stage 3: V=256 ----
    qbp_kernel<256><<<dim3(1, 2), 256, 0, stream>>>(vtxC, 256, r2c, idx3, nd3);
    fout_kernel<<<(512 * 160 + 255) / 256, 256, 0, stream>>>(fmC, w[6], bw[6], fout, 512, 192, 256);
    act32_kernel<<<dim3(256, 2), 128, 0, stream>>>(nd3, idx3, fout, dir[6], fmC, 256, 256, 192, 1);
    fout_kernel<<<(512 * 160 + 255) / 256, 256, 0, stream>>>(fmC, w[7], bw[7], fout, 512, 224, 256);
    act32_kernel<<<dim3(256, 2), 128, 0, stream>>>(nd3, idx3, fout, dir[7], fmC, 256, 256, 224, 1);

    // ---- layer 8 + head ----
    fout8_kernel<<<dim3(20, 32), 256, 0, stream>>>(fmC, w[8], bw[8], fout);
    act8_kernel<<<dim3(256, 2), 256, 0, stream>>>(nd3, idx3, fout, dir[8], fm8);
    gmax_kernel<<<8, 256, 0, stream>>>(fm8, gfeat);
    head_kernel<<<2, 256, 0, stream>>>(gfeat, cw1, cb1, bg, bbv, cw2, cb2, out);
}

// Round 3
// 768.400 us; speedup vs baseline: 2.1890x; 2.1890x over previous
//
#include <hip/hip_runtime.h>
#include <stdint.h>
#include <math.h>

#define NS 32   // nsample
// S = 4, oc = 32 for layers 1..7 (5*oc = 160 fout cols), layer 8: oc=1024 (5120 cols)

// ---------------- threefry2x32 (exact JAX semantics) ----------------
__device__ __forceinline__ void threefry(uint32_t k0, uint32_t k1,
                                         uint32_t x0, uint32_t x1,
                                         uint32_t& o0, uint32_t& o1)
{
    uint32_t ks0 = k0, ks1 = k1, ks2 = k0 ^ k1 ^ 0x1BD11BDAu;
    x0 += ks0; x1 += ks1;
    const int rotA[4] = {13, 15, 26, 6};
    const int rotB[4] = {17, 29, 16, 24};
    uint32_t ks[3] = {ks0, ks1, ks2};
#pragma unroll
    for (int i = 0; i < 5; ++i) {
        const int* r = (i & 1) ? rotB : rotA;
#pragma unroll
        for (int j = 0; j < 4; ++j) {
            x0 += x1;
            x1 = (x1 << r[j]) | (x1 >> (32 - r[j]));
            x1 ^= x0;
        }
        x0 += ks[(i + 1) % 3];
        x1 += ks[(i + 2) % 3] + (uint32_t)(i + 1);
    }
    o0 = x0; o1 = x1;
}

// PARTITIONABLE-mode keys for round `round` of jax _shuffle(key(seed), arange(n)).
//   split(key)  : key' = TF(key,(0,0)), subkey = TF(key,(0,1))   (fold_in-based)
//   bits32[i]   : o0 ^ o1 of TF(subkey,(hi=0, lo=i))             (64-bit counter)
__global__ void perm_genkeys(uint32_t* __restrict__ keys, int* __restrict__ val,
                             uint32_t seed, int round, int n, int initval)
{
    int i = blockIdx.x * blockDim.x + threadIdx.x;
    if (i >= n) return;
    uint32_t k0 = 0u, k1 = seed;
    for (int r = 0; r < round; ++r) {           // advance key chain: key = TF(key,(0,0))
        uint32_t a0, a1;
        threefry(k0, k1, 0u, 0u, a0, a1);
        k0 = a0; k1 = a1;
    }
    uint32_t s0, s1;
    threefry(k0, k1, 0u, 1u, s0, s1);           // subkey = TF(key,(0,1))
    uint32_t y0, y1;
    threefry(s0, s1, 0u, (uint32_t)i, y0, y1);  // counter hi=0, lo=i
    keys[i] = y0 ^ y1;                          // 32-bit fold of the two output words
    if (initval) val[i] = i;
}

// stable ascending rank-scatter: vout[rank(i)] = vin[i]
template <int N>
__global__ void perm_rank(const uint32_t* __restrict__ keys,
                          const int* __restrict__ vin, int* __restrict__ vout)
{
    __shared__ uint32_t sk[N];
    for (int j = threadIdx.x; j < N; j += blockDim.x) sk[j] = keys[j];
    __syncthreads();
    int i = blockIdx.x * blockDim.x + threadIdx.x;
    if (i >= N) return;
    uint32_t k = sk[i];
    int rank = 0;
    for (int j = 0; j < N; ++j) {
        uint32_t kj = sk[j];
        rank += (int)((kj < k) | ((kj == k) & (j < i)));
    }
    vout[rank] = vin[i];
}

// ---------------- wave-parallel query_ball_point + neighbor directions ----------------
// one wave (64 lanes) per query vertex; 64-point chunks; ballot + prefix-popc
// preserves ascending index order; early-exit at 32 found.
__global__ void qbp_wave_kernel(const float* __restrict__ pts, int Vv, float r2,
                                int* __restrict__ idx, float* __restrict__ nd)
{
#pragma clang fp contract(off)
    int b = blockIdx.y;
    int v = blockIdx.x * 4 + (threadIdx.x >> 6);
    int lane = threadIdx.x & 63;
    if (v >= Vv) return;
    const float* P = pts + (size_t)b * Vv * 3;
    float qx = P[v * 3 + 0], qy = P[v * 3 + 1], qz = P[v * 3 + 2];
    float aa = (qx * qx + qy * qy) + qz * qz;
    int* orow = idx + ((size_t)b * Vv + v) * NS;
    float* nrow = nd + ((size_t)b * Vv + v) * NS * 3;
    int cnt = 0;
    int fj = 0; float fx = 0.f, fy = 0.f, fz = 0.f;
    bool have_first = false;
    for (int j0 = 0; j0 < Vv; j0 += 64) {       // Vv is a multiple of 64
        int j = j0 + lane;
        float px = P[j * 3 + 0], py = P[j * 3 + 1], pz = P[j * 3 + 2];
        float bb2 = (px * px + py * py) + pz * pz;
        float dot = (qx * px + qy * py) + qz * pz;
        float d2 = (aa + bb2) - 2.0f * dot;     // matches aa+bb-2*einsum
        bool in = (d2 <= r2);                   // reference masks d2 > r^2
        unsigned long long m = __ballot(in);
        if (m) {
            float dx = px - qx, dy = py - qy, dz = pz - qz;
            float nn = sqrtf((dx * dx + dy * dy) + dz * dz);
            float mm = fmaxf(nn, 1e-12f);
            float ndx = dx / mm, ndy = dy / mm, ndz = dz / mm;
            int rank = __popcll(m & ((1ULL << lane) - 1ULL));
            int pos = cnt + rank;
            if (in && pos < NS) {
                orow[pos] = j;
                nrow[pos * 3 + 0] = ndx;
                nrow[pos * 3 + 1] = ndy;
                nrow[pos * 3 + 2] = ndz;
            }
            if (!have_first) {                  // capture first (lowest-index) neighbor
                int src = __ffsll((unsigned long long)m) - 1;
                fj = __shfl(j, src, 64);
                fx = __shfl(ndx, src, 64);
                fy = __shfl(ndy, src, 64);
                fz = __shfl(ndz, src, 64);
                have_first = true;
            }
            cnt += (int)__popcll(m);
            if (cnt >= NS) break;
        }
    }
    if (cnt < NS) {                             // pad with first neighbor
        int k = cnt + lane;
        if (k < NS) {
            orow[k] = fj;
            nrow[k * 3 + 0] = fx; nrow[k * 3 + 1] = fy; nrow[k * 3 + 2] = fz;
        }
    }
}

// ---------------- conv_surface (oc=32, K=S*32=128) ----------------
__global__ void conv_surface_kernel(const float* __restrict__ nd, const float* __restrict__ dirs,
                                    float* __restrict__ fm, int Vv, int Cstr, int coff)
{
    __shared__ float snd[NS * 3];
    __shared__ float sm[128];
    int b = blockIdx.y, v = blockIdx.x, t = threadIdx.x;
    size_t row = (size_t)b * Vv + v;
    if (t < NS * 3) snd[t] = nd[row * NS * 3 + t];
    __syncthreads();
    float w0 = dirs[t], w1 = dirs[128 + t], w2 = dirs[256 + t];
    float nn = sqrtf(w0 * w0 + w1 * w1 + w2 * w2);
    float mm = fmaxf(nn, 1e-12f);
    w0 /= mm; w1 /= mm; w2 /= mm;
    float mx = -INFINITY;
#pragma unroll
    for (int n = 0; n < NS; ++n) {
        float th = fmaxf(snd[n * 3] * w0 + snd[n * 3 + 1] * w1 + snd[n * 3 + 2] * w2, 0.0f);
        mx = fmaxf(mx, th);
    }
    sm[t] = mx;
    __syncthreads();
    if (t < 32) {
        float o = ((sm[t] + sm[32 + t]) + sm[64 + t]) + sm[96 + t];  // sum over S
        o = fmaxf(o, 0.0f);                                          // outer relu
        fm[row * Cstr + coff + t] = o;
    }
}

// ---------------- fout = fm[:, :ic] @ W + b  (cols = 160) ----------------
__global__ void fout_kernel(const float* __restrict__ fm, const float* __restrict__ W,
                            const float* __restrict__ bias, float* __restrict__ fout,
                            int rows, int ic, int Cstr)
{
    int tid = blockIdx.x * blockDim.x + threadIdx.x;
    if (tid >= rows * 160) return;
    int row = tid / 160, col = tid - row * 160;
    const float* fr = fm + (size_t)row * Cstr;
    float acc = 0.f;
    for (int i = 0; i < ic; ++i) acc += fr[i] * W[i * 160 + col];
    fout[(size_t)row * 160 + col] = acc + bias[col];
}

// ---------------- conv_layer act (oc=32): center + max_n(theta*support) summed over S ----
__global__ void act32_kernel(const float* __restrict__ nd, const int* __restrict__ idx,
                             const float* __restrict__ fout, const float* __restrict__ dirs,
                             float* __restrict__ fm, int Vv, int Cstr, int coff, int dorelu)
{
    __shared__ float snd[NS * 3];
    __shared__ int sidx[NS];
    __shared__ float sm[128];
    int b = blockIdx.y, v = blockIdx.x, t = threadIdx.x;
    size_t row = (size_t)b * Vv + v;
    if (t < NS * 3) snd[t] = nd[row * NS * 3 + t];
    if (t < NS) sidx[t] = idx[row * NS + t];
    __syncthreads();
    float w0 = dirs[t], w1 = dirs[128 + t], w2 = dirs[256 + t];
    float nn = sqrtf(w0 * w0 + w1 * w1 + w2 * w2);
    float mm = fmaxf(nn, 1e-12f);
    w0 /= mm; w1 /= mm; w2 /= mm;
    float mx = -INFINITY;
    for (int n = 0; n < NS; ++n) {
        float th = fmaxf(snd[n * 3] * w0 + snd[n * 3 + 1] * w1 + snd[n * 3 + 2] * w2, 0.0f);
        float sup = fout[((size_t)b * Vv + sidx[n]) * 160 + 32 + t];
        mx = fmaxf(mx, th * sup);
    }
    sm[t] = mx;
    __syncthreads();
    if (t < 32) {
        float act = ((sm[t] + sm[32 + t]) + sm[64 + t]) + sm[96 + t];
        float o = fout[row * 160 + t] + act;           // center + act
        if (dorelu) o = fmaxf(o, 0.0f);
        fm[row * Cstr + coff + t] = o;
    }
}

// ---------------- pool: gather-max over first 4 neighbors at permuted rows ----------------
__global__ void pool_kernel(const float* __restrict__ fmin, const int* __restrict__ idxp,
                            const int* __restrict__ perm, const float* __restrict__ vin,
                            float* __restrict__ fmout, float* __restrict__ vout,
                            int Vin, int Vout, int Cin, int Cout)
{
    int b = blockIdx.y, nv = blockIdx.x, t = threadIdx.x;
    int pv = perm[nv];
    size_t inrow = (size_t)b * Vin + pv;
    const int* ir = idxp + inrow * NS;   // radius/pointset identical -> first 4 of 32-idx
    int j0 = ir[0], j1 = ir[1], j2 = ir[2], j3 = ir[3];
    if (t < Cin) {
        const float* base = fmin + (size_t)b * Vin * Cin;
        float m = base[(size_t)j0 * Cin + t];
        m = fmaxf(m, base[(size_t)j1 * Cin + t]);
        m = fmaxf(m, base[(size_t)j2 * Cin + t]);
        m = fmaxf(m, base[(size_t)j3 * Cin + t]);
        fmout[((size_t)b * Vout + nv) * Cout + t] = m;
    }
    if (t == 0) {
        vout[((size_t)b * Vout + nv) * 3 + 0] = vin[inrow * 3 + 0];
        vout[((size_t)b * Vout + nv) * 3 + 1] = vin[inrow * 3 + 1];
        vout[((size_t)b * Vout + nv) * 3 + 2] = vin[inrow * 3 + 2];
    }
}

// ---------------- layer-8 GEMM: (512 x 256) @ (256 x 5120) + b ----------------
__global__ void fout8_kernel(const float* __restrict__ fm, const float* __restrict__ W,
                             const float* __restrict__ bias, float* __restrict__ out)
{
    __shared__ float sA[16 * 256];   // 16 rows x full K
    __shared__ float sB[32 * 256];   // 32 k x 256 cols
    int ct = blockIdx.x, rt = blockIdx.y, t = threadIdx.x;
    int row0 = rt * 16, col0 = ct * 256;
    for (int i = t; i < 16 * 256; i += 256) {
        int r = i >> 8, k = i & 255;
        sA[i] = fm[(size_t)(row0 + r) * 256 + k];
    }
    float acc[16];
#pragma unroll
    for (int r = 0; r < 16; ++r) acc[r] = 0.f;
    for (int kt = 0; kt < 256; kt += 32) {
        __syncthreads();
        for (int i = t; i < 32 * 256; i += 256) {
            int k = i >> 8, c = i & 255;
            sB[i] = W[(size_t)(kt + k) * 5120 + col0 + c];
        }
        __syncthreads();
#pragma unroll 8
        for (int k = 0; k < 32; ++k) {
            float bv = sB[k * 256 + t];
#pragma unroll
            for (int r = 0; r < 16; ++r) acc[r] += sA[r * 256 + kt + k] * bv;
        }
    }
    float bb = bias[col0 + t];
#pragma unroll
    for (int r = 0; r < 16; ++r)
        out[(size_t)(row0 + r) * 5120 + col0 + t] = acc[r] + bb;
}

// ---------------- layer-8 act (oc=1024, K=S*1024=4096) ----------------
__global__ void act8_kernel(const float* __restrict__ nd, const int* __restrict__ idx,
                            const float* __restrict__ fout8, const float* __restrict__ dir8,
                            float* __restrict__ fm8)
{
    __shared__ float sdx[4096], sdy[4096], sdz[4096];   // 48 KB normalized dirs
    __shared__ float snd[NS * 3];
    __shared__ int sidx[NS];
    int b = blockIdx.y, v = blockIdx.x, t = threadIdx.x;
    for (int c = t; c < 4096; c += 256) {
        float w0 = dir8[c], w1 = dir8[4096 + c], w2 = dir8[8192 + c];
        float nn = sqrtf(w0 * w0 + w1 * w1 + w2 * w2);
        float mm = fmaxf(nn, 1e-12f);
        sdx[c] = w0 / mm; sdy[c] = w1 / mm; sdz[c] = w2 / mm;
    }
    size_t row = (size_t)b * 256 + v;
    if (t < NS * 3) snd[t] = nd[row * NS * 3 + t];
    if (t < NS) sidx[t] = idx[row * NS + t];
    __syncthreads();
    float mx[16];
#pragma unroll
    for (int u = 0; u < 16; ++u) mx[u] = -INFINITY;
    for (int n = 0; n < NS; ++n) {
        float a0 = snd[n * 3], a1 = snd[n * 3 + 1], a2 = snd[n * 3 + 2];
        const float* sup = fout8 + ((size_t)b * 256 + sidx[n]) * 5120 + 1024;
#pragma unroll
        for (int u = 0; u < 16; ++u) {
            int k = t + 256 * u;
            float th = fmaxf(a0 * sdx[k] + a1 * sdy[k] + a2 * sdz[k], 0.0f);
            mx[u] = fmaxf(mx[u], th * sup[k]);
        }
    }
    // k = t + 256u -> s = u>>2, c = t + 256*(u&3): S-reduction is thread-local
    const float* crow = fout8 + row * 5120;
#pragma unroll
    for (int w = 0; w < 4; ++w) {
        int c = t + 256 * w;
        float act = ((mx[w] + mx[4 + w]) + mx[8 + w]) + mx[12 + w];
        fm8[row * 1024 + c] = crow[c] + act;            // no relu on fm8
    }
}

// ---------------- global max over vertices ----------------
__global__ void gmax_kernel(const float* __restrict__ fm8, float* __restrict__ gfeat)
{
    int t = blockIdx.x * blockDim.x + threadIdx.x;  // 0..2047
    if (t >= 2048) return;
    int b = t >> 10, c = t & 1023;
    float m = -INFINITY;
    for (int v = 0; v < 256; ++v) m = fmaxf(m, fm8[((size_t)b * 256 + v) * 1024 + c]);
    gfeat[t] = m;
}

// ---------------- classifier head ----------------
__global__ void head_kernel(const float* __restrict__ gfeat,
                            const float* __restrict__ cw1, const float* __restrict__ cb1,
                            const float* __restrict__ bg, const float* __restrict__ bbv,
                            const float* __restrict__ cw2, const float* __restrict__ cb2,
                            float* __restrict__ out)
{
    __shared__ float sg[1024];
    __shared__ float sh[256];
    int b = blockIdx.x, t = threadIdx.x;
    for (int i = t; i < 1024; i += 256) sg[i] = gfeat[b * 1024 + i];
    __syncthreads();
    float acc = 0.f;
    for (int i = 0; i < 1024; ++i) acc += sg[i] * cw1[i * 256 + t];
    float h = acc + cb1[t];
    const float s = sqrtf((float)(1.0 + 1e-5));
    h = h / s * bg[t] + bbv[t];
    h = fmaxf(h, 0.0f);
    sh[t] = h;
    __syncthreads();
    if (t < 40) {
        float a = 0.f;
        for (int i = 0; i < 256; ++i) a += sh[i] * cw2[i * 40 + t];
        out[b * 40 + t] = a + cb2[t];
    }
}

// ==================================================================
extern "C" void kernel_launch(void* const* d_in, const int* in_sizes, int n_in,
                              void* d_out, int out_size, void* d_ws, size_t ws_size,
                              hipStream_t stream)
{
    (void)in_sizes; (void)n_in; (void)out_size; (void)ws_size;
    const float* vertices = (const float*)d_in[0];
    const float* d0 = (const float*)d_in[1];
    const float *w[9], *bw[9], *dir[9];
    for (int i = 1; i <= 8; ++i) {
        w[i]   = (const float*)d_in[2 + (i - 1) * 3];
        bw[i]  = (const float*)d_in[3 + (i - 1) * 3];
        dir[i] = (const float*)d_in[4 + (i - 1) * 3];
    }
    const float* cw1 = (const float*)d_in[26];
    const float* cb1 = (const float*)d_in[27];
    const float* bg  = (const float*)d_in[28];
    const float* bbv = (const float*)d_in[29];
    const float* cw2 = (const float*)d_in[30];
    const float* cb2 = (const float*)d_in[31];
    float* out = (float*)d_out;

    char* ws = (char*)d_ws;
    size_t off = 0;
    auto take = [&](size_t bytes) -> char* {
        char* p = ws + off;
        off = (off + bytes + 255) & ~(size_t)255;
        return p;
    };
    uint32_t* keys1 = (uint32_t*)take(4096 * 4);
    int* valA = (int*)take(4096 * 4);
    int* valB = (int*)take(4096 * 4);
    uint32_t* keys2 = (uint32_t*)take(1024 * 4);
    int* v2A = (int*)take(1024 * 4);
    int* v2B = (int*)take(1024 * 4);
    int*   idx1 = (int*)take((size_t)2 * 4096 * NS * 4);
    float* nd1  = (float*)take((size_t)2 * 4096 * NS * 3 * 4);
    float* fmA  = (float*)take((size_t)2 * 4096 * 96 * 4);
    float* vtxB = (float*)take((size_t)2 * 1024 * 3 * 4);
    int*   idx2 = (int*)take((size_t)2 * 1024 * NS * 4);
    float* nd2  = (float*)take((size_t)2 * 1024 * NS * 3 * 4);
    float* fmB  = (float*)take((size_t)2 * 1024 * 192 * 4);
    float* vtxC = (float*)take((size_t)2 * 256 * 3 * 4);
    int*   idx3 = (int*)take((size_t)2 * 256 * NS * 4);
    float* nd3  = (float*)take((size_t)2 * 256 * NS * 3 * 4);
    float* fmC  = (float*)take((size_t)2 * 256 * 256 * 4);
    float* fm8  = (float*)take((size_t)2 * 256 * 1024 * 4);
    float* gfeat = (float*)take(2 * 1024 * 4);
    float* fout = (float*)take((size_t)512 * 5120 * 4);  // shared by all fout layers

    // permutations (jax.random.permutation, partitionable threefry;
    // 2 sort rounds for n=4096, 1 for n=1024)
    perm_genkeys<<<16, 256, 0, stream>>>(keys1, valA, 1u, 0, 4096, 1);
    perm_rank<4096><<<16, 256, 0, stream>>>(keys1, valA, valB);
    perm_genkeys<<<16, 256, 0, stream>>>(keys1, valA, 1u, 1, 4096, 0);
    perm_rank<4096><<<16, 256, 0, stream>>>(keys1, valB, valA);   // perm1 = valA[:1024]
    perm_genkeys<<<4, 256, 0, stream>>>(keys2, v2A, 2u, 0, 1024, 1);
    perm_rank<1024><<<4, 256, 0, stream>>>(keys2, v2A, v2B);      // perm2 = v2B[:256]

    const float r2a = (float)(0.2 * 0.2), r2b = (float)(0.4 * 0.4), r2c = (float)(0.6 * 0.6);

    // ---- stage 1: V=4096 ----
    qbp_wave_kernel<<<dim3(1024, 2), 256, 0, stream>>>(vertices, 4096, r2a, idx1, nd1);
    conv_surface_kernel<<<dim3(4096, 2), 128, 0, stream>>>(nd1, d0, fmA, 4096, 96, 0);
    fout_kernel<<<(8192 * 160 + 255) / 256, 256, 0, stream>>>(fmA, w[1], bw[1], fout, 8192, 32, 96);
    act32_kernel<<<dim3(4096, 2), 128, 0, stream>>>(nd1, idx1, fout, dir[1], fmA, 4096, 96, 32, 1);
    fout_kernel<<<(8192 * 160 + 255) / 256, 256, 0, stream>>>(fmA, w[2], bw[2], fout, 8192, 64, 96);
    act32_kernel<<<dim3(4096, 2), 128, 0, stream>>>(nd1, idx1, fout, dir[2], fmA, 4096, 96, 64, 1);
    pool_kernel<<<dim3(1024, 2), 128, 0, stream>>>(fmA, idx1, valA, vertices, fmB, vtxB, 4096, 1024, 96, 192);

    // ---- stage 2: V=1024 ----
    qbp_wave_kernel<<<dim3(256, 2), 256, 0, stream>>>(vtxB, 1024, r2b, idx2, nd2);
    fout_kernel<<<(2048 * 160 + 255) / 256, 256, 0, stream>>>(fmB, w[3], bw[3], fout, 2048, 96, 192);
    act32_kernel<<<dim3(1024, 2), 128, 0, stream>>>(nd2, idx2, fout, dir[3], fmB, 1024, 192, 96, 1);
    fout_kernel<<<(2048 * 160 + 255) / 256, 256, 0, stream>>>(fmB, w[4], bw[4], fout, 2048, 128, 192);
    act32_kernel<<<dim3(1024, 2), 128, 0, stream>>>(nd2, idx2, fout, dir[4], fmB, 1024, 192, 128, 1);
    fout_kernel<<<(2048 * 160 + 255) / 256, 256, 0, stream>>>(fmB, w[5], bw[5], fout, 2048, 160, 192);
    act32_kernel<<<dim3(1024, 2), 128, 0, stream>>>(nd2, idx2, fout, dir[5], fmB, 1024, 192, 160, 1);
    pool_kernel<<<dim3(256, 2), 256, 0, stream>>>(fmB, idx2, v2B, vtxB, fmC, vtxC, 1024, 256, 192, 256);

    // ---- stage 3: V=256 ----
    qbp_wave_kernel<<<dim3(64, 2), 256, 0, stream>>>(vtxC, 256, r2c, idx3, nd3);
    fout_kernel<<<(512 * 160 + 255) / 256, 256, 0, stream>>>(fmC, w[6], bw[6], fout, 512, 192, 256);
    act32_kernel<<<dim3(256, 2), 128, 0, stream>>>(nd3, idx3, fout, dir[6], fmC, 256, 256, 192, 1);
    fout_kernel<<<(512 * 160 + 255) / 256, 256, 0, stream>>>(fmC, w[7], bw[7], fout, 512, 224, 256);
    act32_kernel<<<dim3(256, 2), 128, 0, stream>>>(nd3, idx3, fout, dir[7], fmC, 256, 256, 224, 1);

    // ---- layer 8 + head ----
    fout8_kernel<<<dim3(20, 32), 256, 0, stream>>>(fmC, w[8], bw[8], fout);
    act8_kernel<<<dim3(256, 2), 256, 0, stream>>>(nd3, idx3, fout, dir[8], fm8);
    gmax_kernel<<<8, 256, 0, stream>>>(fm8, gfeat);
    head_kernel<<<2, 256, 0, stream>>>(gfeat, cw1, cb1, bg, bbv, cw2, cb2, out);
}

// Round 4
// 551.428 us; speedup vs baseline: 3.0503x; 1.3935x over previous
//
#include <hip/hip_runtime.h>
#include <stdint.h>
#include <math.h>

#define NS 32   // nsample
// S = 4, oc = 32 for layers 1..7 (5*oc = 160 fout cols), layer 8: oc=1024 (5120 cols)

// ---------------- threefry2x32 (exact JAX semantics) ----------------
__device__ __forceinline__ void threefry(uint32_t k0, uint32_t k1,
                                         uint32_t x0, uint32_t x1,
                                         uint32_t& o0, uint32_t& o1)
{
    uint32_t ks0 = k0, ks1 = k1, ks2 = k0 ^ k1 ^ 0x1BD11BDAu;
    x0 += ks0; x1 += ks1;
    const int rotA[4] = {13, 15, 26, 6};
    const int rotB[4] = {17, 29, 16, 24};
    uint32_t ks[3] = {ks0, ks1, ks2};
#pragma unroll
    for (int i = 0; i < 5; ++i) {
        const int* r = (i & 1) ? rotB : rotA;
#pragma unroll
        for (int j = 0; j < 4; ++j) {
            x0 += x1;
            x1 = (x1 << r[j]) | (x1 >> (32 - r[j]));
            x1 ^= x0;
        }
        x0 += ks[(i + 1) % 3];
        x1 += ks[(i + 2) % 3] + (uint32_t)(i + 1);
    }
    o0 = x0; o1 = x1;
}

// PARTITIONABLE-mode keys for round `round` of jax _shuffle(key(seed), arange(n)).
//   split(key)  : key' = TF(key,(0,0)), subkey = TF(key,(0,1))   (fold_in-based)
//   bits32[i]   : o0 ^ o1 of TF(subkey,(hi=0, lo=i))             (64-bit counter)
__global__ void perm_genkeys(uint32_t* __restrict__ keys, int* __restrict__ val,
                             uint32_t seed, int round, int n, int initval)
{
    int i = blockIdx.x * blockDim.x + threadIdx.x;
    if (i >= n) return;
    uint32_t k0 = 0u, k1 = seed;
    for (int r = 0; r < round; ++r) {           // advance key chain: key = TF(key,(0,0))
        uint32_t a0, a1;
        threefry(k0, k1, 0u, 0u, a0, a1);
        k0 = a0; k1 = a1;
    }
    uint32_t s0, s1;
    threefry(k0, k1, 0u, 1u, s0, s1);           // subkey = TF(key,(0,1))
    uint32_t y0, y1;
    threefry(s0, s1, 0u, (uint32_t)i, y0, y1);  // counter hi=0, lo=i
    keys[i] = y0 ^ y1;                          // 32-bit fold of the two output words
    if (initval) val[i] = i;
}

// stable ascending rank-scatter, wave-parallel: one wave per element.
// rank(i) = #{j : kj<k || (kj==k && j<i)}; vout[rank] = vin[i].
template <int N>
__global__ void perm_rank(const uint32_t* __restrict__ keys,
                          const int* __restrict__ vin, int* __restrict__ vout)
{
    __shared__ uint32_t sk[N];
    for (int j = threadIdx.x; j < N; j += blockDim.x) sk[j] = keys[j];
    __syncthreads();
    int w = threadIdx.x >> 6, lane = threadIdx.x & 63;
    int i = blockIdx.x * 4 + w;                 // 4 waves per 256-thread block
    uint32_t k = sk[i];
    int c = 0;
    for (int j = lane; j < N; j += 64) {
        uint32_t kj = sk[j];
        c += (int)((kj < k) | ((kj == k) & (j < i)));
    }
#pragma unroll
    for (int m = 1; m < 64; m <<= 1) c += __shfl_xor(c, m, 64);
    if (lane == 0) vout[c] = vin[i];
}

// ---------------- wave-parallel query_ball_point + neighbor directions ----------------
// one wave (64 lanes) per query vertex; 64-point chunks; ballot + prefix-popc
// preserves ascending index order; early-exit at 32 found.
__global__ void qbp_wave_kernel(const float* __restrict__ pts, int Vv, float r2,
                                int* __restrict__ idx, float* __restrict__ nd)
{
#pragma clang fp contract(off)
    int b = blockIdx.y;
    int v = blockIdx.x * 4 + (threadIdx.x >> 6);
    int lane = threadIdx.x & 63;
    if (v >= Vv) return;
    const float* P = pts + (size_t)b * Vv * 3;
    float qx = P[v * 3 + 0], qy = P[v * 3 + 1], qz = P[v * 3 + 2];
    float aa = (qx * qx + qy * qy) + qz * qz;
    int* orow = idx + ((size_t)b * Vv + v) * NS;
    float* nrow = nd + ((size_t)b * Vv + v) * NS * 3;
    int cnt = 0;
    int fj = 0; float fx = 0.f, fy = 0.f, fz = 0.f;
    bool have_first = false;
    for (int j0 = 0; j0 < Vv; j0 += 64) {       // Vv is a multiple of 64
        int j = j0 + lane;
        float px = P[j * 3 + 0], py = P[j * 3 + 1], pz = P[j * 3 + 2];
        float bb2 = (px * px + py * py) + pz * pz;
        float dot = (qx * px + qy * py) + qz * pz;
        float d2 = (aa + bb2) - 2.0f * dot;     // matches aa+bb-2*einsum
        bool in = (d2 <= r2);                   // reference masks d2 > r^2
        unsigned long long m = __ballot(in);
        if (m) {
            float dx = px - qx, dy = py - qy, dz = pz - qz;
            float nn = sqrtf((dx * dx + dy * dy) + dz * dz);
            float mm = fmaxf(nn, 1e-12f);
            float ndx = dx / mm, ndy = dy / mm, ndz = dz / mm;
            int rank = __popcll(m & ((1ULL << lane) - 1ULL));
            int pos = cnt + rank;
            if (in && pos < NS) {
                orow[pos] = j;
                nrow[pos * 3 + 0] = ndx;
                nrow[pos * 3 + 1] = ndy;
                nrow[pos * 3 + 2] = ndz;
            }
            if (!have_first) {                  // capture first (lowest-index) neighbor
                int src = __ffsll((unsigned long long)m) - 1;
                fj = __shfl(j, src, 64);
                fx = __shfl(ndx, src, 64);
                fy = __shfl(ndy, src, 64);
                fz = __shfl(ndz, src, 64);
                have_first = true;
            }
            cnt += (int)__popcll(m);
            if (cnt >= NS) break;
        }
    }
    if (cnt < NS) {                             // pad with first neighbor
        int k = cnt + lane;
        if (k < NS) {
            orow[k] = fj;
            nrow[k * 3 + 0] = fx; nrow[k * 3 + 1] = fy; nrow[k * 3 + 2] = fz;
        }
    }
}

// ---------------- conv_surface (oc=32, K=S*32=128) ----------------
__global__ void conv_surface_kernel(const float* __restrict__ nd, const float* __restrict__ dirs,
                                    float* __restrict__ fm, int Vv, int Cstr, int coff)
{
    __shared__ float snd[NS * 3];
    __shared__ float sm[128];
    int b = blockIdx.y, v = blockIdx.x, t = threadIdx.x;
    size_t row = (size_t)b * Vv + v;
    if (t < NS * 3) snd[t] = nd[row * NS * 3 + t];
    __syncthreads();
    float w0 = dirs[t], w1 = dirs[128 + t], w2 = dirs[256 + t];
    float nn = sqrtf(w0 * w0 + w1 * w1 + w2 * w2);
    float mm = fmaxf(nn, 1e-12f);
    w0 /= mm; w1 /= mm; w2 /= mm;
    float mx = -INFINITY;
#pragma unroll
    for (int n = 0; n < NS; ++n) {
        float th = fmaxf(snd[n * 3] * w0 + snd[n * 3 + 1] * w1 + snd[n * 3 + 2] * w2, 0.0f);
        mx = fmaxf(mx, th);
    }
    sm[t] = mx;
    __syncthreads();
    if (t < 32) {
        float o = ((sm[t] + sm[32 + t]) + sm[64 + t]) + sm[96 + t];  // sum over S
        o = fmaxf(o, 0.0f);                                          // outer relu
        fm[row * Cstr + coff + t] = o;
    }
}

// ---------------- fout = fm[:, :ic] @ W + b  (cols = 160) ----------------
__global__ void fout_kernel(const float* __restrict__ fm, const float* __restrict__ W,
                            const float* __restrict__ bias, float* __restrict__ fout,
                            int rows, int ic, int Cstr)
{
    int tid = blockIdx.x * blockDim.x + threadIdx.x;
    if (tid >= rows * 160) return;
    int row = tid / 160, col = tid - row * 160;
    const float* fr = fm + (size_t)row * Cstr;
    float acc = 0.f;
    for (int i = 0; i < ic; ++i) acc += fr[i] * W[i * 160 + col];
    fout[(size_t)row * 160 + col] = acc + bias[col];
}

// ---------------- conv_layer act (oc=32): center + max_n(theta*support) summed over S ----
__global__ void act32_kernel(const float* __restrict__ nd, const int* __restrict__ idx,
                             const float* __restrict__ fout, const float* __restrict__ dirs,
                             float* __restrict__ fm, int Vv, int Cstr, int coff, int dorelu)
{
    __shared__ float snd[NS * 3];
    __shared__ int sidx[NS];
    __shared__ float sm[128];
    int b = blockIdx.y, v = blockIdx.x, t = threadIdx.x;
    size_t row = (size_t)b * Vv + v;
    if (t < NS * 3) snd[t] = nd[row * NS * 3 + t];
    if (t < NS) sidx[t] = idx[row * NS + t];
    __syncthreads();
    float w0 = dirs[t], w1 = dirs[128 + t], w2 = dirs[256 + t];
    float nn = sqrtf(w0 * w0 + w1 * w1 + w2 * w2);
    float mm = fmaxf(nn, 1e-12f);
    w0 /= mm; w1 /= mm; w2 /= mm;
    float mx = -INFINITY;
    for (int n = 0; n < NS; ++n) {
        float th = fmaxf(snd[n * 3] * w0 + snd[n * 3 + 1] * w1 + snd[n * 3 + 2] * w2, 0.0f);
        float sup = fout[((size_t)b * Vv + sidx[n]) * 160 + 32 + t];
        mx = fmaxf(mx, th * sup);
    }
    sm[t] = mx;
    __syncthreads();
    if (t < 32) {
        float act = ((sm[t] + sm[32 + t]) + sm[64 + t]) + sm[96 + t];
        float o = fout[row * 160 + t] + act;           // center + act
        if (dorelu) o = fmaxf(o, 0.0f);
        fm[row * Cstr + coff + t] = o;
    }
}

// ---------------- pool: gather-max over first 4 neighbors at permuted rows ----------------
__global__ void pool_kernel(const float* __restrict__ fmin, const int* __restrict__ idxp,
                            const int* __restrict__ perm, const float* __restrict__ vin,
                            float* __restrict__ fmout, float* __restrict__ vout,
                            int Vin, int Vout, int Cin, int Cout)
{
    int b = blockIdx.y, nv = blockIdx.x, t = threadIdx.x;
    int pv = perm[nv];
    size_t inrow = (size_t)b * Vin + pv;
    const int* ir = idxp + inrow * NS;   // radius/pointset identical -> first 4 of 32-idx
    int j0 = ir[0], j1 = ir[1], j2 = ir[2], j3 = ir[3];
    if (t < Cin) {
        const float* base = fmin + (size_t)b * Vin * Cin;
        float m = base[(size_t)j0 * Cin + t];
        m = fmaxf(m, base[(size_t)j1 * Cin + t]);
        m = fmaxf(m, base[(size_t)j2 * Cin + t]);
        m = fmaxf(m, base[(size_t)j3 * Cin + t]);
        fmout[((size_t)b * Vout + nv) * Cout + t] = m;
    }
    if (t == 0) {
        vout[((size_t)b * Vout + nv) * 3 + 0] = vin[inrow * 3 + 0];
        vout[((size_t)b * Vout + nv) * 3 + 1] = vin[inrow * 3 + 1];
        vout[((size_t)b * Vout + nv) * 3 + 2] = vin[inrow * 3 + 2];
    }
}

// ---------------- layer-8 GEMM: (512 x 256) @ (256 x 5120) + b ----------------
__global__ void fout8_kernel(const float* __restrict__ fm, const float* __restrict__ W,
                             const float* __restrict__ bias, float* __restrict__ out)
{
    __shared__ float sA[16 * 256];   // 16 rows x full K
    __shared__ float sB[32 * 256];   // 32 k x 256 cols
    int ct = blockIdx.x, rt = blockIdx.y, t = threadIdx.x;
    int row0 = rt * 16, col0 = ct * 256;
    for (int i = t; i < 16 * 256; i += 256) {
        int r = i >> 8, k = i & 255;
        sA[i] = fm[(size_t)(row0 + r) * 256 + k];
    }
    float acc[16];
#pragma unroll
    for (int r = 0; r < 16; ++r) acc[r] = 0.f;
    for (int kt = 0; kt < 256; kt += 32) {
        __syncthreads();
        for (int i = t; i < 32 * 256; i += 256) {
            int k = i >> 8, c = i & 255;
            sB[i] = W[(size_t)(kt + k) * 5120 + col0 + c];
        }
        __syncthreads();
#pragma unroll 8
        for (int k = 0; k < 32; ++k) {
            float bv = sB[k * 256 + t];
#pragma unroll
            for (int r = 0; r < 16; ++r) acc[r] += sA[r * 256 + kt + k] * bv;
        }
    }
    float bb = bias[col0 + t];
#pragma unroll
    for (int r = 0; r < 16; ++r)
        out[(size_t)(row0 + r) * 5120 + col0 + t] = acc[r] + bb;
}

// ---------------- layer-8 act (oc=1024, K=S*1024=4096) ----------------
__global__ void act8_kernel(const float* __restrict__ nd, const int* __restrict__ idx,
                            const float* __restrict__ fout8, const float* __restrict__ dir8,
                            float* __restrict__ fm8)
{
    __shared__ float sdx[4096], sdy[4096], sdz[4096];   // 48 KB normalized dirs
    __shared__ float snd[NS * 3];
    __shared__ int sidx[NS];
    int b = blockIdx.y, v = blockIdx.x, t = threadIdx.x;
    for (int c = t; c < 4096; c += 256) {
        float w0 = dir8[c], w1 = dir8[4096 + c], w2 = dir8[8192 + c];
        float nn = sqrtf(w0 * w0 + w1 * w1 + w2 * w2);
        float mm = fmaxf(nn, 1e-12f);
        sdx[c] = w0 / mm; sdy[c] = w1 / mm; sdz[c] = w2 / mm;
    }
    size_t row = (size_t)b * 256 + v;
    if (t < NS * 3) snd[t] = nd[row * NS * 3 + t];
    if (t < NS) sidx[t] = idx[row * NS + t];
    __syncthreads();
    float mx[16];
#pragma unroll
    for (int u = 0; u < 16; ++u) mx[u] = -INFINITY;
    for (int n = 0; n < NS; ++n) {
        float a0 = snd[n * 3], a1 = snd[n * 3 + 1], a2 = snd[n * 3 + 2];
        const float* sup = fout8 + ((size_t)b * 256 + sidx[n]) * 5120 + 1024;
#pragma unroll
        for (int u = 0; u < 16; ++u) {
            int k = t + 256 * u;
            float th = fmaxf(a0 * sdx[k] + a1 * sdy[k] + a2 * sdz[k], 0.0f);
            mx[u] = fmaxf(mx[u], th * sup[k]);
        }
    }
    // k = t + 256u -> s = u>>2, c = t + 256*(u&3): S-reduction is thread-local
    const float* crow = fout8 + row * 5120;
#pragma unroll
    for (int w = 0; w < 4; ++w) {
        int c = t + 256 * w;
        float act = ((mx[w] + mx[4 + w]) + mx[8 + w]) + mx[12 + w];
        fm8[row * 1024 + c] = crow[c] + act;            // no relu on fm8
    }
}

// ---------------- global max over vertices ----------------
__global__ void gmax_kernel(const float* __restrict__ fm8, float* __restrict__ gfeat)
{
    int t = blockIdx.x * blockDim.x + threadIdx.x;  // 0..2047
    if (t >= 2048) return;
    int b = t >> 10, c = t & 1023;
    float m = -INFINITY;
    for (int v = 0; v < 256; ++v) m = fmaxf(m, fm8[((size_t)b * 256 + v) * 1024 + c]);
    gfeat[t] = m;
}

// ---------------- classifier head ----------------
__global__ void head_kernel(const float* __restrict__ gfeat,
                            const float* __restrict__ cw1, const float* __restrict__ cb1,
                            const float* __restrict__ bg, const float* __restrict__ bbv,
                            const float* __restrict__ cw2, const float* __restrict__ cb2,
                            float* __restrict__ out)
{
    __shared__ float sg[1024];
    __shared__ float sh[256];
    int b = blockIdx.x, t = threadIdx.x;
    for (int i = t; i < 1024; i += 256) sg[i] = gfeat[b * 1024 + i];
    __syncthreads();
    float acc = 0.f;
    for (int i = 0; i < 1024; ++i) acc += sg[i] * cw1[i * 256 + t];
    float h = acc + cb1[t];
    const float s = sqrtf((float)(1.0 + 1e-5));
    h = h / s * bg[t] + bbv[t];
    h = fmaxf(h, 0.0f);
    sh[t] = h;
    __syncthreads();
    if (t < 40) {
        float a = 0.f;
        for (int i = 0; i < 256; ++i) a += sh[i] * cw2[i * 40 + t];
        out[b * 40 + t] = a + cb2[t];
    }
}

// ==================================================================
extern "C" void kernel_launch(void* const* d_in, const int* in_sizes, int n_in,
                              void* d_out, int out_size, void* d_ws, size_t ws_size,
                              hipStream_t stream)
{
    (void)in_sizes; (void)n_in; (void)out_size; (void)ws_size;
    const float* vertices = (const float*)d_in[0];
    const float* d0 = (const float*)d_in[1];
    const float *w[9], *bw[9], *dir[9];
    for (int i = 1; i <= 8; ++i) {
        w[i]   = (const float*)d_in[2 + (i - 1) * 3];
        bw[i]  = (const float*)d_in[3 + (i - 1) * 3];
        dir[i] = (const float*)d_in[4 + (i - 1) * 3];
    }
    const float* cw1 = (const float*)d_in[26];
    const float* cb1 = (const float*)d_in[27];
    const float* bg  = (const float*)d_in[28];
    const float* bbv = (const float*)d_in[29];
    const float* cw2 = (const float*)d_in[30];
    const float* cb2 = (const float*)d_in[31];
    float* out = (float*)d_out;

    char* ws = (char*)d_ws;
    size_t off = 0;
    auto take = [&](size_t bytes) -> char* {
        char* p = ws + off;
        off = (off + bytes + 255) & ~(size_t)255;
        return p;
    };
    uint32_t* keys1 = (uint32_t*)take(4096 * 4);
    int* valA = (int*)take(4096 * 4);
    int* valB = (int*)take(4096 * 4);
    uint32_t* keys2 = (uint32_t*)take(1024 * 4);
    int* v2A = (int*)take(1024 * 4);
    int* v2B = (int*)take(1024 * 4);
    int*   idx1 = (int*)take((size_t)2 * 4096 * NS * 4);
    float* nd1  = (float*)take((size_t)2 * 4096 * NS * 3 * 4);
    float* fmA  = (float*)take((size_t)2 * 4096 * 96 * 4);
    float* vtxB = (float*)take((size_t)2 * 1024 * 3 * 4);
    int*   idx2 = (int*)take((size_t)2 * 1024 * NS * 4);
    float* nd2  = (float*)take((size_t)2 * 1024 * NS * 3 * 4);
    float* fmB  = (float*)take((size_t)2 * 1024 * 192 * 4);
    float* vtxC = (float*)take((size_t)2 * 256 * 3 * 4);
    int*   idx3 = (int*)take((size_t)2 * 256 * NS * 4);
    float* nd3  = (float*)take((size_t)2 * 256 * NS * 3 * 4);
    float* fmC  = (float*)take((size_t)2 * 256 * 256 * 4);
    float* fm8  = (float*)take((size_t)2 * 256 * 1024 * 4);
    float* gfeat = (float*)take(2 * 1024 * 4);
    float* fout = (float*)take((size_t)512 * 5120 * 4);  // shared by all fout layers

    // permutations (jax.random.permutation, partitionable threefry;
    // 2 sort rounds for n=4096, 1 for n=1024)
    perm_genkeys<<<16, 256, 0, stream>>>(keys1, valA, 1u, 0, 4096, 1);
    perm_rank<4096><<<1024, 256, 0, stream>>>(keys1, valA, valB);
    perm_genkeys<<<16, 256, 0, stream>>>(keys1, valA, 1u, 1, 4096, 0);
    perm_rank<4096><<<1024, 256, 0, stream>>>(keys1, valB, valA);   // perm1 = valA[:1024]
    perm_genkeys<<<4, 256, 0, stream>>>(keys2, v2A, 2u, 0, 1024, 1);
    perm_rank<1024><<<256, 256, 0, stream>>>(keys2, v2A, v2B);      // perm2 = v2B[:256]

    const float r2a = (float)(0.2 * 0.2), r2b = (float)(0.4 * 0.4), r2c = (float)(0.6 * 0.6);

    // ---- stage 1: V=4096 ----
    qbp_wave_kernel<<<dim3(1024, 2), 256, 0, stream>>>(vertices, 4096, r2a, idx1, nd1);
    conv_surface_kernel<<<dim3(4096, 2), 128, 0, stream>>>(nd1, d0, fmA, 4096, 96, 0);
    fout_kernel<<<(8192 * 160 + 255) / 256, 256, 0, stream>>>(fmA, w[1], bw[1], fout, 8192, 32, 96);
    act32_kernel<<<dim3(4096, 2), 128, 0, stream>>>(nd1, idx1, fout, dir[1], fmA, 4096, 96, 32, 1);
    fout_kernel<<<(8192 * 160 + 255) / 256, 256, 0, stream>>>(fmA, w[2], bw[2], fout, 8192, 64, 96);
    act32_kernel<<<dim3(4096, 2), 128, 0, stream>>>(nd1, idx1, fout, dir[2], fmA, 4096, 96, 64, 1);
    pool_kernel<<<dim3(1024, 2), 128, 0, stream>>>(fmA, idx1, valA, vertices, fmB, vtxB, 4096, 1024, 96, 192);

    // ---- stage 2: V=1024 ----
    qbp_wave_kernel<<<dim3(256, 2), 256, 0, stream>>>(vtxB, 1024, r2b, idx2, nd2);
    fout_kernel<<<(2048 * 160 + 255) / 256, 256, 0, stream>>>(fmB, w[3], bw[3], fout, 2048, 96, 192);
    act32_kernel<<<dim3(1024, 2), 128, 0, stream>>>(nd2, idx2, fout, dir[3], fmB, 1024, 192, 96, 1);
    fout_kernel<<<(2048 * 160 + 255) / 256, 256, 0, stream>>>(fmB, w[4], bw[4], fout, 2048, 128, 192);
    act32_kernel<<<dim3(1024, 2), 128, 0, stream>>>(nd2, idx2, fout, dir[4], fmB, 1024, 192, 128, 1);
    fout_kernel<<<(2048 * 160 + 255) / 256, 256, 0, stream>>>(fmB, w[5], bw[5], fout, 2048, 160, 192);
    act32_kernel<<<dim3(1024, 2), 128, 0, stream>>>(nd2, idx2, fout, dir[5], fmB, 1024, 192, 160, 1);
    pool_kernel<<<dim3(256, 2), 256, 0, stream>>>(fmB, idx2, v2B, vtxB, fmC, vtxC, 1024, 256, 192, 256);

    // ---- stage 3: V=256 ----
    qbp_wave_kernel<<<dim3(64, 2), 256, 0, stream>>>(vtxC, 256, r2c, idx3, nd3);
    fout_kernel<<<(512 * 160 + 255) / 256, 256, 0, stream>>>(fmC, w[6], bw[6], fout, 512, 192, 256);
    act32_kernel<<<dim3(256, 2), 128, 0, stream>>>(nd3, idx3, fout, dir[6], fmC, 256, 256, 192, 1);
    fout_kernel<<<(512 * 160 + 255) / 256, 256, 0, stream>>>(fmC, w[7], bw[7], fout, 512, 224, 256);
    act32_kernel<<<dim3(256, 2), 128, 0, stream>>>(nd3, idx3, fout, dir[7], fmC, 256, 256, 224, 1);

    // ---- layer 8 + head ----
    fout8_kernel<<<dim3(20, 32), 256, 0, stream>>>(fmC, w[8], bw[8], fout);
    act8_kernel<<<dim3(256, 2), 256, 0, stream>>>(nd3, idx3, fout, dir[8], fm8);
    gmax_kernel<<<8, 256, 0, stream>>>(fm8, gfeat);
    head_kernel<<<2, 256, 0, stream>>>(gfeat, cw1, cb1, bg, bbv, cw2, cb2, out);
}

// Round 5
// 331.854 us; speedup vs baseline: 5.0685x; 1.6617x over previous
//
#include <hip/hip_runtime.h>
#include <stdint.h>
#include <math.h>

#define NS 32   // nsample
// S = 4, oc = 32 for layers 1..7 (5*oc = 160 fout cols), layer 8: oc=1024 (5120 cols)

// ---------------- threefry2x32 (exact JAX semantics) ----------------
__device__ __forceinline__ void threefry(uint32_t k0, uint32_t k1,
                                         uint32_t x0, uint32_t x1,
                                         uint32_t& o0, uint32_t& o1)
{
    uint32_t ks0 = k0, ks1 = k1, ks2 = k0 ^ k1 ^ 0x1BD11BDAu;
    x0 += ks0; x1 += ks1;
    const int rotA[4] = {13, 15, 26, 6};
    const int rotB[4] = {17, 29, 16, 24};
    uint32_t ks[3] = {ks0, ks1, ks2};
#pragma unroll
    for (int i = 0; i < 5; ++i) {
        const int* r = (i & 1) ? rotB : rotA;
#pragma unroll
        for (int j = 0; j < 4; ++j) {
            x0 += x1;
            x1 = (x1 << r[j]) | (x1 >> (32 - r[j]));
            x1 ^= x0;
        }
        x0 += ks[(i + 1) % 3];
        x1 += ks[(i + 2) % 3] + (uint32_t)(i + 1);
    }
    o0 = x0; o1 = x1;
}

// PARTITIONABLE-mode keys for round `round` of jax _shuffle(key(seed), arange(n)).
//   split(key)  : key' = TF(key,(0,0)), subkey = TF(key,(0,1))   (fold_in-based)
//   bits32[i]   : o0 ^ o1 of TF(subkey,(hi=0, lo=i))             (64-bit counter)
__global__ void perm_genkeys(uint32_t* __restrict__ keys, int* __restrict__ val,
                             uint32_t seed, int round, int n, int initval)
{
    int i = blockIdx.x * blockDim.x + threadIdx.x;
    if (i >= n) return;
    uint32_t k0 = 0u, k1 = seed;
    for (int r = 0; r < round; ++r) {           // advance key chain: key = TF(key,(0,0))
        uint32_t a0, a1;
        threefry(k0, k1, 0u, 0u, a0, a1);
        k0 = a0; k1 = a1;
    }
    uint32_t s0, s1;
    threefry(k0, k1, 0u, 1u, s0, s1);           // subkey = TF(key,(0,1))
    uint32_t y0, y1;
    threefry(s0, s1, 0u, (uint32_t)i, y0, y1);  // counter hi=0, lo=i
    keys[i] = y0 ^ y1;                          // 32-bit fold of the two output words
    if (initval) val[i] = i;
}

// stable ascending rank-scatter, wave-parallel: one wave per element.
// rank(i) = #{j : kj<k || (kj==k && j<i)}; vout[rank] = vin[i].
template <int N>
__global__ void perm_rank(const uint32_t* __restrict__ keys,
                          const int* __restrict__ vin, int* __restrict__ vout)
{
    __shared__ uint32_t sk[N];
    for (int j = threadIdx.x; j < N; j += blockDim.x) sk[j] = keys[j];
    __syncthreads();
    int w = threadIdx.x >> 6, lane = threadIdx.x & 63;
    int i = blockIdx.x * 4 + w;                 // 4 waves per 256-thread block
    uint32_t k = sk[i];
    int c = 0;
    for (int j = lane; j < N; j += 64) {
        uint32_t kj = sk[j];
        c += (int)((kj < k) | ((kj == k) & (j < i)));
    }
#pragma unroll
    for (int m = 1; m < 64; m <<= 1) c += __shfl_xor(c, m, 64);
    if (lane == 0) vout[c] = vin[i];
}

// ---------------- wave-parallel query_ball_point + neighbor directions ----------------
// one wave (64 lanes) per query vertex; 64-point chunks; ballot + prefix-popc
// preserves ascending index order; early-exit at 32 found.
__global__ void qbp_wave_kernel(const float* __restrict__ pts, int Vv, float r2,
                                int* __restrict__ idx, float* __restrict__ nd)
{
#pragma clang fp contract(off)
    int b = blockIdx.y;
    int v = blockIdx.x * 4 + (threadIdx.x >> 6);
    int lane = threadIdx.x & 63;
    if (v >= Vv) return;
    const float* P = pts + (size_t)b * Vv * 3;
    float qx = P[v * 3 + 0], qy = P[v * 3 + 1], qz = P[v * 3 + 2];
    float aa = (qx * qx + qy * qy) + qz * qz;
    int* orow = idx + ((size_t)b * Vv + v) * NS;
    float* nrow = nd + ((size_t)b * Vv + v) * NS * 3;
    int cnt = 0;
    int fj = 0; float fx = 0.f, fy = 0.f, fz = 0.f;
    bool have_first = false;
    for (int j0 = 0; j0 < Vv; j0 += 64) {       // Vv is a multiple of 64
        int j = j0 + lane;
        float px = P[j * 3 + 0], py = P[j * 3 + 1], pz = P[j * 3 + 2];
        float bb2 = (px * px + py * py) + pz * pz;
        float dot = (qx * px + qy * py) + qz * pz;
        float d2 = (aa + bb2) - 2.0f * dot;     // matches aa+bb-2*einsum
        bool in = (d2 <= r2);                   // reference masks d2 > r^2
        unsigned long long m = __ballot(in);
        if (m) {
            float dx = px - qx, dy = py - qy, dz = pz - qz;
            float nn = sqrtf((dx * dx + dy * dy) + dz * dz);
            float mm = fmaxf(nn, 1e-12f);
            float ndx = dx / mm, ndy = dy / mm, ndz = dz / mm;
            int rank = __popcll(m & ((1ULL << lane) - 1ULL));
            int pos = cnt + rank;
            if (in && pos < NS) {
                orow[pos] = j;
                nrow[pos * 3 + 0] = ndx;
                nrow[pos * 3 + 1] = ndy;
                nrow[pos * 3 + 2] = ndz;
            }
            if (!have_first) {                  // capture first (lowest-index) neighbor
                int src = __ffsll((unsigned long long)m) - 1;
                fj = __shfl(j, src, 64);
                fx = __shfl(ndx, src, 64);
                fy = __shfl(ndy, src, 64);
                fz = __shfl(ndz, src, 64);
                have_first = true;
            }
            cnt += (int)__popcll(m);
            if (cnt >= NS) break;
        }
    }
    if (cnt < NS) {                             // pad with first neighbor
        int k = cnt + lane;
        if (k < NS) {
            orow[k] = fj;
            nrow[k * 3 + 0] = fx; nrow[k * 3 + 1] = fy; nrow[k * 3 + 2] = fz;
        }
    }
}

// ---------------- conv_surface (oc=32, K=S*32=128) ----------------
__global__ void conv_surface_kernel(const float* __restrict__ nd, const float* __restrict__ dirs,
                                    float* __restrict__ fm, int Vv, int Cstr, int coff)
{
    __shared__ float snd[NS * 3];
    __shared__ float sm[128];
    int b = blockIdx.y, v = blockIdx.x, t = threadIdx.x;
    size_t row = (size_t)b * Vv + v;
    if (t < NS * 3) snd[t] = nd[row * NS * 3 + t];
    __syncthreads();
    float w0 = dirs[t], w1 = dirs[128 + t], w2 = dirs[256 + t];
    float nn = sqrtf(w0 * w0 + w1 * w1 + w2 * w2);
    float mm = fmaxf(nn, 1e-12f);
    w0 /= mm; w1 /= mm; w2 /= mm;
    float mx = -INFINITY;
#pragma unroll
    for (int n = 0; n < NS; ++n) {
        float th = fmaxf(snd[n * 3] * w0 + snd[n * 3 + 1] * w1 + snd[n * 3 + 2] * w2, 0.0f);
        mx = fmaxf(mx, th);
    }
    sm[t] = mx;
    __syncthreads();
    if (t < 32) {
        float o = ((sm[t] + sm[32 + t]) + sm[64 + t]) + sm[96 + t];  // sum over S
        o = fmaxf(o, 0.0f);                                          // outer relu
        fm[row * Cstr + coff + t] = o;
    }
}

// ---------------- tiled GEMM: C[rows x N] = A[rows x K (stride lda)] @ W[K x N] + b ----
// BM=128, BN=32, BK=32; 256 threads; 4x4 micro-tile per thread.
// Requires rows%128==0, N%32==0, K%32==0 (all call sites satisfy this).
__global__ void gemm_kernel(const float* __restrict__ A, const float* __restrict__ W,
                            const float* __restrict__ bias, float* __restrict__ C,
                            int K, int N, int lda)
{
    const int BM = 128, BN = 32, BK = 32;
    __shared__ float sA[BK][BM + 4];   // sA[k][m] = A[bm+m][k0+k]
    __shared__ float sB[BK][BN + 4];   // sB[k][n] = W[k0+k][bn+n]
    int t = threadIdx.x;
    int bm = blockIdx.y * BM, bn = blockIdx.x * BN;
    int tm = t & 31, tn = t >> 5;      // rows tm*4.., cols tn*4..
    float acc[4][4] = {{0.f}};
    for (int k0 = 0; k0 < K; k0 += BK) {
        // stage A: 128 rows x 32 k, float4 per thread x4
#pragma unroll
        for (int i = 0; i < 4; ++i) {
            int q = t + i * 256;               // [0,1024)
            int m = q >> 3, kq = q & 7;        // m in [0,128), k4 = kq*4
            float4 a = *(const float4*)&A[(size_t)(bm + m) * lda + k0 + kq * 4];
            sA[kq * 4 + 0][m] = a.x;
            sA[kq * 4 + 1][m] = a.y;
            sA[kq * 4 + 2][m] = a.z;
            sA[kq * 4 + 3][m] = a.w;
        }
        // stage B: 32 k x 32 n, one float4 per thread
        {
            int n4 = t & 7, k = t >> 3;        // k in [0,32)
            float4 bv = *(const float4*)&W[(size_t)(k0 + k) * N + bn + n4 * 4];
            *(float4*)&sB[k][n4 * 4] = bv;
        }
        __syncthreads();
#pragma unroll
        for (int k = 0; k < BK; ++k) {
            float4 a4 = *(const float4*)&sA[k][tm * 4];
            float4 b4 = *(const float4*)&sB[k][tn * 4];
            float av[4] = {a4.x, a4.y, a4.z, a4.w};
            float bv[4] = {b4.x, b4.y, b4.z, b4.w};
#pragma unroll
            for (int i = 0; i < 4; ++i)
#pragma unroll
                for (int j = 0; j < 4; ++j)
                    acc[i][j] += av[i] * bv[j];
        }
        __syncthreads();
    }
    float4 bb = *(const float4*)&bias[bn + tn * 4];
    float bvv[4] = {bb.x, bb.y, bb.z, bb.w};
#pragma unroll
    for (int i = 0; i < 4; ++i) {
        float4 o;
        o.x = acc[i][0] + bvv[0];
        o.y = acc[i][1] + bvv[1];
        o.z = acc[i][2] + bvv[2];
        o.w = acc[i][3] + bvv[3];
        *(float4*)&C[(size_t)(bm + tm * 4 + i) * N + bn + tn * 4] = o;
    }
}

// ---------------- conv_layer act (oc=32): center + max_n(theta*support) summed over S ----
__global__ void act32_kernel(const float* __restrict__ nd, const int* __restrict__ idx,
                             const float* __restrict__ fout, const float* __restrict__ dirs,
                             float* __restrict__ fm, int Vv, int Cstr, int coff, int dorelu)
{
    __shared__ float snd[NS * 3];
    __shared__ int sidx[NS];
    __shared__ float sm[128];
    int b = blockIdx.y, v = blockIdx.x, t = threadIdx.x;
    size_t row = (size_t)b * Vv + v;
    if (t < NS * 3) snd[t] = nd[row * NS * 3 + t];
    if (t < NS) sidx[t] = idx[row * NS + t];
    __syncthreads();
    float w0 = dirs[t], w1 = dirs[128 + t], w2 = dirs[256 + t];
    float nn = sqrtf(w0 * w0 + w1 * w1 + w2 * w2);
    float mm = fmaxf(nn, 1e-12f);
    w0 /= mm; w1 /= mm; w2 /= mm;
    float mx = -INFINITY;
    for (int n = 0; n < NS; ++n) {
        float th = fmaxf(snd[n * 3] * w0 + snd[n * 3 + 1] * w1 + snd[n * 3 + 2] * w2, 0.0f);
        float sup = fout[((size_t)b * Vv + sidx[n]) * 160 + 32 + t];
        mx = fmaxf(mx, th * sup);
    }
    sm[t] = mx;
    __syncthreads();
    if (t < 32) {
        float act = ((sm[t] + sm[32 + t]) + sm[64 + t]) + sm[96 + t];
        float o = fout[row * 160 + t] + act;           // center + act
        if (dorelu) o = fmaxf(o, 0.0f);
        fm[row * Cstr + coff + t] = o;
    }
}

// ---------------- pool: gather-max over first 4 neighbors at permuted rows ----------------
__global__ void pool_kernel(const float* __restrict__ fmin, const int* __restrict__ idxp,
                            const int* __restrict__ perm, const float* __restrict__ vin,
                            float* __restrict__ fmout, float* __restrict__ vout,
                            int Vin, int Vout, int Cin, int Cout)
{
    int b = blockIdx.y, nv = blockIdx.x, t = threadIdx.x;
    int pv = perm[nv];
    size_t inrow = (size_t)b * Vin + pv;
    const int* ir = idxp + inrow * NS;   // radius/pointset identical -> first 4 of 32-idx
    int j0 = ir[0], j1 = ir[1], j2 = ir[2], j3 = ir[3];
    if (t < Cin) {
        const float* base = fmin + (size_t)b * Vin * Cin;
        float m = base[(size_t)j0 * Cin + t];
        m = fmaxf(m, base[(size_t)j1 * Cin + t]);
        m = fmaxf(m, base[(size_t)j2 * Cin + t]);
        m = fmaxf(m, base[(size_t)j3 * Cin + t]);
        fmout[((size_t)b * Vout + nv) * Cout + t] = m;
    }
    if (t == 0) {
        vout[((size_t)b * Vout + nv) * 3 + 0] = vin[inrow * 3 + 0];
        vout[((size_t)b * Vout + nv) * 3 + 1] = vin[inrow * 3 + 1];
        vout[((size_t)b * Vout + nv) * 3 + 2] = vin[inrow * 3 + 2];
    }
}

// ---------------- layer-8 act (oc=1024, K=S*1024=4096) ----------------
__global__ void act8_kernel(const float* __restrict__ nd, const int* __restrict__ idx,
                            const float* __restrict__ fout8, const float* __restrict__ dir8,
                            float* __restrict__ fm8)
{
    __shared__ float sdx[4096], sdy[4096], sdz[4096];   // 48 KB normalized dirs
    __shared__ float snd[NS * 3];
    __shared__ int sidx[NS];
    int b = blockIdx.y, v = blockIdx.x, t = threadIdx.x;
    for (int c = t; c < 4096; c += 256) {
        float w0 = dir8[c], w1 = dir8[4096 + c], w2 = dir8[8192 + c];
        float nn = sqrtf(w0 * w0 + w1 * w1 + w2 * w2);
        float mm = fmaxf(nn, 1e-12f);
        sdx[c] = w0 / mm; sdy[c] = w1 / mm; sdz[c] = w2 / mm;
    }
    size_t row = (size_t)b * 256 + v;
    if (t < NS * 3) snd[t] = nd[row * NS * 3 + t];
    if (t < NS) sidx[t] = idx[row * NS + t];
    __syncthreads();
    float mx[16];
#pragma unroll
    for (int u = 0; u < 16; ++u) mx[u] = -INFINITY;
    for (int n = 0; n < NS; ++n) {
        float a0 = snd[n * 3], a1 = snd[n * 3 + 1], a2 = snd[n * 3 + 2];
        const float* sup = fout8 + ((size_t)b * 256 + sidx[n]) * 5120 + 1024;
#pragma unroll
        for (int u = 0; u < 16; ++u) {
            int k = t + 256 * u;
            float th = fmaxf(a0 * sdx[k] + a1 * sdy[k] + a2 * sdz[k], 0.0f);
            mx[u] = fmaxf(mx[u], th * sup[k]);
        }
    }
    // k = t + 256u -> s = u>>2, c = t + 256*(u&3): S-reduction is thread-local
    const float* crow = fout8 + row * 5120;
#pragma unroll
    for (int w = 0; w < 4; ++w) {
        int c = t + 256 * w;
        float act = ((mx[w] + mx[4 + w]) + mx[8 + w]) + mx[12 + w];
        fm8[row * 1024 + c] = crow[c] + act;            // no relu on fm8
    }
}

// ---------------- global max over vertices ----------------
__global__ void gmax_kernel(const float* __restrict__ fm8, float* __restrict__ gfeat)
{
    int t = blockIdx.x * blockDim.x + threadIdx.x;  // 0..2047
    if (t >= 2048) return;
    int b = t >> 10, c = t & 1023;
    float m = -INFINITY;
    for (int v = 0; v < 256; ++v) m = fmaxf(m, fm8[((size_t)b * 256 + v) * 1024 + c]);
    gfeat[t] = m;
}

// ---------------- classifier head ----------------
__global__ void head_kernel(const float* __restrict__ gfeat,
                            const float* __restrict__ cw1, const float* __restrict__ cb1,
                            const float* __restrict__ bg, const float* __restrict__ bbv,
                            const float* __restrict__ cw2, const float* __restrict__ cb2,
                            float* __restrict__ out)
{
    __shared__ float sg[1024];
    __shared__ float sh[256];
    int b = blockIdx.x, t = threadIdx.x;
    for (int i = t; i < 1024; i += 256) sg[i] = gfeat[b * 1024 + i];
    __syncthreads();
    float acc = 0.f;
    for (int i = 0; i < 1024; ++i) acc += sg[i] * cw1[i * 256 + t];
    float h = acc + cb1[t];
    const float s = sqrtf((float)(1.0 + 1e-5));
    h = h / s * bg[t] + bbv[t];
    h = fmaxf(h, 0.0f);
    sh[t] = h;
    __syncthreads();
    if (t < 40) {
        float a = 0.f;
        for (int i = 0; i < 256; ++i) a += sh[i] * cw2[i * 40 + t];
        out[b * 40 + t] = a + cb2[t];
    }
}

// ==================================================================
extern "C" void kernel_launch(void* const* d_in, const int* in_sizes, int n_in,
                              void* d_out, int out_size, void* d_ws, size_t ws_size,
                              hipStream_t stream)
{
    (void)in_sizes; (void)n_in; (void)out_size; (void)ws_size;
    const float* vertices = (const float*)d_in[0];
    const float* d0 = (const float*)d_in[1];
    const float *w[9], *bw[9], *dir[9];
    for (int i = 1; i <= 8; ++i) {
        w[i]   = (const float*)d_in[2 + (i - 1) * 3];
        bw[i]  = (const float*)d_in[3 + (i - 1) * 3];
        dir[i] = (const float*)d_in[4 + (i - 1) * 3];
    }
    const float* cw1 = (const float*)d_in[26];
    const float* cb1 = (const float*)d_in[27];
    const float* bg  = (const float*)d_in[28];
    const float* bbv = (const float*)d_in[29];
    const float* cw2 = (const float*)d_in[30];
    const float* cb2 = (const float*)d_in[31];
    float* out = (float*)d_out;

    char* ws = (char*)d_ws;
    size_t off = 0;
    auto take = [&](size_t bytes) -> char* {
        char* p = ws + off;
        off = (off + bytes + 255) & ~(size_t)255;
        return p;
    };
    uint32_t* keys1 = (uint32_t*)take(4096 * 4);
    int* valA = (int*)take(4096 * 4);
    int* valB = (int*)take(4096 * 4);
    uint32_t* keys2 = (uint32_t*)take(1024 * 4);
    int* v2A = (int*)take(1024 * 4);
    int* v2B = (int*)take(1024 * 4);
    int*   idx1 = (int*)take((size_t)2 * 4096 * NS * 4);
    float* nd1  = (float*)take((size_t)2 * 4096 * NS * 3 * 4);
    float* fmA  = (float*)take((size_t)2 * 4096 * 96 * 4);
    float* vtxB = (float*)take((size_t)2 * 1024 * 3 * 4);
    int*   idx2 = (int*)take((size_t)2 * 1024 * NS * 4);
    float* nd2  = (float*)take((size_t)2 * 1024 * NS * 3 * 4);
    float* fmB  = (float*)take((size_t)2 * 1024 * 192 * 4);
    float* vtxC = (float*)take((size_t)2 * 256 * 3 * 4);
    int*   idx3 = (int*)take((size_t)2 * 256 * NS * 4);
    float* nd3  = (float*)take((size_t)2 * 256 * NS * 3 * 4);
    float* fmC  = (float*)take((size_t)2 * 256 * 256 * 4);
    float* fm8  = (float*)take((size_t)2 * 256 * 1024 * 4);
    float* gfeat = (float*)take(2 * 1024 * 4);
    float* fout = (float*)take((size_t)512 * 5120 * 4);  // shared by all fout layers

    // permutations (jax.random.permutation, partitionable threefry;
    // 2 sort rounds for n=4096, 1 for n=1024)
    perm_genkeys<<<16, 256, 0, stream>>>(keys1, valA, 1u, 0, 4096, 1);
    perm_rank<4096><<<1024, 256, 0, stream>>>(keys1, valA, valB);
    perm_genkeys<<<16, 256, 0, stream>>>(keys1, valA, 1u, 1, 4096, 0);
    perm_rank<4096><<<1024, 256, 0, stream>>>(keys1, valB, valA);   // perm1 = valA[:1024]
    perm_genkeys<<<4, 256, 0, stream>>>(keys2, v2A, 2u, 0, 1024, 1);
    perm_rank<1024><<<256, 256, 0, stream>>>(keys2, v2A, v2B);      // perm2 = v2B[:256]

    const float r2a = (float)(0.2 * 0.2), r2b = (float)(0.4 * 0.4), r2c = (float)(0.6 * 0.6);

    // ---- stage 1: V=4096 ----
    qbp_wave_kernel<<<dim3(1024, 2), 256, 0, stream>>>(vertices, 4096, r2a, idx1, nd1);
    conv_surface_kernel<<<dim3(4096, 2), 128, 0, stream>>>(nd1, d0, fmA, 4096, 96, 0);
    gemm_kernel<<<dim3(5, 64), 256, 0, stream>>>(fmA, w[1], bw[1], fout, 32, 160, 96);
    act32_kernel<<<dim3(4096, 2), 128, 0, stream>>>(nd1, idx1, fout, dir[1], fmA, 4096, 96, 32, 1);
    gemm_kernel<<<dim3(5, 64), 256, 0, stream>>>(fmA, w[2], bw[2], fout, 64, 160, 96);
    act32_kernel<<<dim3(4096, 2), 128, 0, stream>>>(nd1, idx1, fout, dir[2], fmA, 4096, 96, 64, 1);
    pool_kernel<<<dim3(1024, 2), 128, 0, stream>>>(fmA, idx1, valA, vertices, fmB, vtxB, 4096, 1024, 96, 192);

    // ---- stage 2: V=1024 ----
    qbp_wave_kernel<<<dim3(256, 2), 256, 0, stream>>>(vtxB, 1024, r2b, idx2, nd2);
    gemm_kernel<<<dim3(5, 16), 256, 0, stream>>>(fmB, w[3], bw[3], fout, 96, 160, 192);
    act32_kernel<<<dim3(1024, 2), 128, 0, stream>>>(nd2, idx2, fout, dir[3], fmB, 1024, 192, 96, 1);
    gemm_kernel<<<dim3(5, 16), 256, 0, stream>>>(fmB, w[4], bw[4], fout, 128, 160, 192);
    act32_kernel<<<dim3(1024, 2), 128, 0, stream>>>(nd2, idx2, fout, dir[4], fmB, 1024, 192, 128, 1);
    gemm_kernel<<<dim3(5, 16), 256, 0, stream>>>(fmB, w[5], bw[5], fout, 160, 160, 192);
    act32_kernel<<<dim3(1024, 2), 128, 0, stream>>>(nd2, idx2, fout, dir[5], fmB, 1024, 192, 160, 1);
    pool_kernel<<<dim3(256, 2), 256, 0, stream>>>(fmB, idx2, v2B, vtxB, fmC, vtxC, 1024, 256, 192, 256);

    // ---- stage 3: V=256 ----
    qbp_wave_kernel<<<dim3(64, 2), 256, 0, stream>>>(vtxC, 256, r2c, idx3, nd3);
    gemm_kernel<<<dim3(5, 4), 256, 0, stream>>>(fmC, w[6], bw[6], fout, 192, 160, 256);
    act32_kernel<<<dim3(256, 2), 128, 0, stream>>>(nd3, idx3, fout, dir[6], fmC, 256, 256, 192, 1);
    gemm_kernel<<<dim3(5, 4), 256, 0, stream>>>(fmC, w[7], bw[7], fout, 224, 160, 256);
    act32_kernel<<<dim3(256, 2), 128, 0, stream>>>(nd3, idx3, fout, dir[7], fmC, 256, 256, 224, 1);

    // ---- layer 8 + head ----
    gemm_kernel<<<dim3(160, 4), 256, 0, stream>>>(fmC, w[8], bw[8], fout, 256, 5120, 256);
    act8_kernel<<<dim3(256, 2), 256, 0, stream>>>(nd3, idx3, fout, dir[8], fm8);
    gmax_kernel<<<8, 256, 0, stream>>>(fm8, gfeat);
    head_kernel<<<2, 256, 0, stream>>>(gfeat, cw1, cb1, bg, bbv, cw2, cb2, out);
}

// Round 6
// 276.130 us; speedup vs baseline: 6.0914x; 1.2018x over previous
//
#include <hip/hip_runtime.h>
#include <stdint.h>
#include <math.h>

#define NS 32   // nsample
// S = 4, oc = 32 for layers 1..7 (5*oc = 160 fout cols), layer 8: oc=1024 (5120 cols)

// ---------------- threefry2x32 (exact JAX semantics) ----------------
__device__ __forceinline__ void threefry(uint32_t k0, uint32_t k1,
                                         uint32_t x0, uint32_t x1,
                                         uint32_t& o0, uint32_t& o1)
{
    uint32_t ks0 = k0, ks1 = k1, ks2 = k0 ^ k1 ^ 0x1BD11BDAu;
    x0 += ks0; x1 += ks1;
    const int rotA[4] = {13, 15, 26, 6};
    const int rotB[4] = {17, 29, 16, 24};
    uint32_t ks[3] = {ks0, ks1, ks2};
#pragma unroll
    for (int i = 0; i < 5; ++i) {
        const int* r = (i & 1) ? rotB : rotA;
#pragma unroll
        for (int j = 0; j < 4; ++j) {
            x0 += x1;
            x1 = (x1 << r[j]) | (x1 >> (32 - r[j]));
            x1 ^= x0;
        }
        x0 += ks[(i + 1) % 3];
        x1 += ks[(i + 2) % 3] + (uint32_t)(i + 1);
    }
    o0 = x0; o1 = x1;
}

// PARTITIONABLE-mode keys for round `round` of jax _shuffle(key(seed), arange(n)).
//   split(key)  : key' = TF(key,(0,0)), subkey = TF(key,(0,1))   (fold_in-based)
//   bits32[i]   : o0 ^ o1 of TF(subkey,(hi=0, lo=i))             (64-bit counter)
__global__ void perm_genkeys(uint32_t* __restrict__ keys, int* __restrict__ val,
                             uint32_t seed, int round, int n, int initval)
{
    int i = blockIdx.x * blockDim.x + threadIdx.x;
    if (i >= n) return;
    uint32_t k0 = 0u, k1 = seed;
    for (int r = 0; r < round; ++r) {           // advance key chain: key = TF(key,(0,0))
        uint32_t a0, a1;
        threefry(k0, k1, 0u, 0u, a0, a1);
        k0 = a0; k1 = a1;
    }
    uint32_t s0, s1;
    threefry(k0, k1, 0u, 1u, s0, s1);           // subkey = TF(key,(0,1))
    uint32_t y0, y1;
    threefry(s0, s1, 0u, (uint32_t)i, y0, y1);  // counter hi=0, lo=i
    keys[i] = y0 ^ y1;                          // 32-bit fold of the two output words
    if (initval) val[i] = i;
}

// stable ascending rank-scatter, wave-parallel: one wave per element.
// rank(i) = #{j : kj<k || (kj==k && j<i)}; vout[rank] = vin[i].
template <int N>
__global__ void perm_rank(const uint32_t* __restrict__ keys,
                          const int* __restrict__ vin, int* __restrict__ vout)
{
    __shared__ uint32_t sk[N];
    for (int j = threadIdx.x; j < N; j += blockDim.x) sk[j] = keys[j];
    __syncthreads();
    int w = threadIdx.x >> 6, lane = threadIdx.x & 63;
    int i = blockIdx.x * 4 + w;                 // 4 waves per 256-thread block
    uint32_t k = sk[i];
    int c = 0;
    for (int j = lane; j < N; j += 64) {
        uint32_t kj = sk[j];
        c += (int)((kj < k) | ((kj == k) & (j < i)));
    }
#pragma unroll
    for (int m = 1; m < 64; m <<= 1) c += __shfl_xor(c, m, 64);
    if (lane == 0) vout[c] = vin[i];
}

// ---------------- wave-parallel query_ball_point + neighbor directions ----------------
__global__ void qbp_wave_kernel(const float* __restrict__ pts, int Vv, float r2,
                                int* __restrict__ idx, float* __restrict__ nd)
{
#pragma clang fp contract(off)
    int b = blockIdx.y;
    int v = blockIdx.x * 4 + (threadIdx.x >> 6);
    int lane = threadIdx.x & 63;
    if (v >= Vv) return;
    const float* P = pts + (size_t)b * Vv * 3;
    float qx = P[v * 3 + 0], qy = P[v * 3 + 1], qz = P[v * 3 + 2];
    float aa = (qx * qx + qy * qy) + qz * qz;
    int* orow = idx + ((size_t)b * Vv + v) * NS;
    float* nrow = nd + ((size_t)b * Vv + v) * NS * 3;
    int cnt = 0;
    int fj = 0; float fx = 0.f, fy = 0.f, fz = 0.f;
    bool have_first = false;
    for (int j0 = 0; j0 < Vv; j0 += 64) {       // Vv is a multiple of 64
        int j = j0 + lane;
        float px = P[j * 3 + 0], py = P[j * 3 + 1], pz = P[j * 3 + 2];
        float bb2 = (px * px + py * py) + pz * pz;
        float dot = (qx * px + qy * py) + qz * pz;
        float d2 = (aa + bb2) - 2.0f * dot;     // matches aa+bb-2*einsum
        bool in = (d2 <= r2);                   // reference masks d2 > r^2
        unsigned long long m = __ballot(in);
        if (m) {
            float dx = px - qx, dy = py - qy, dz = pz - qz;
            float nn = sqrtf((dx * dx + dy * dy) + dz * dz);
            float mm = fmaxf(nn, 1e-12f);
            float ndx = dx / mm, ndy = dy / mm, ndz = dz / mm;
            int rank = __popcll(m & ((1ULL << lane) - 1ULL));
            int pos = cnt + rank;
            if (in && pos < NS) {
                orow[pos] = j;
                nrow[pos * 3 + 0] = ndx;
                nrow[pos * 3 + 1] = ndy;
                nrow[pos * 3 + 2] = ndz;
            }
            if (!have_first) {                  // capture first (lowest-index) neighbor
                int src = __ffsll((unsigned long long)m) - 1;
                fj = __shfl(j, src, 64);
                fx = __shfl(ndx, src, 64);
                fy = __shfl(ndy, src, 64);
                fz = __shfl(ndz, src, 64);
                have_first = true;
            }
            cnt += (int)__popcll(m);
            if (cnt >= NS) break;
        }
    }
    if (cnt < NS) {                             // pad with first neighbor
        int k = cnt + lane;
        if (k < NS) {
            orow[k] = fj;
            nrow[k * 3 + 0] = fx; nrow[k * 3 + 1] = fy; nrow[k * 3 + 2] = fz;
        }
    }
}

// ---------------- conv_surface (oc=32, K=S*32=128) ----------------
__global__ void conv_surface_kernel(const float* __restrict__ nd, const float* __restrict__ dirs,
                                    float* __restrict__ fm, int Vv, int Cstr, int coff)
{
    __shared__ float snd[NS * 3];
    __shared__ float sm[128];
    int b = blockIdx.y, v = blockIdx.x, t = threadIdx.x;
    size_t row = (size_t)b * Vv + v;
    if (t < NS * 3) snd[t] = nd[row * NS * 3 + t];
    __syncthreads();
    float w0 = dirs[t], w1 = dirs[128 + t], w2 = dirs[256 + t];
    float nn = sqrtf(w0 * w0 + w1 * w1 + w2 * w2);
    float mm = fmaxf(nn, 1e-12f);
    w0 /= mm; w1 /= mm; w2 /= mm;
    float mx = -INFINITY;
#pragma unroll
    for (int n = 0; n < NS; ++n) {
        float th = fmaxf(snd[n * 3] * w0 + snd[n * 3 + 1] * w1 + snd[n * 3 + 2] * w2, 0.0f);
        mx = fmaxf(mx, th);
    }
    sm[t] = mx;
    __syncthreads();
    if (t < 32) {
        float o = ((sm[t] + sm[32 + t]) + sm[64 + t]) + sm[96 + t];  // sum over S
        o = fmaxf(o, 0.0f);                                          // outer relu
        fm[row * Cstr + coff + t] = o;
    }
}

// ---------------- tiled GEMM: C[rows x N] = A[rows x K (stride lda)] @ W[K x N] + b ----
// BM=128, BN=32, BK=32; 256 threads; 4x4 micro-tile per thread.
__global__ void gemm_kernel(const float* __restrict__ A, const float* __restrict__ W,
                            const float* __restrict__ bias, float* __restrict__ C,
                            int K, int N, int lda)
{
    const int BM = 128, BN = 32, BK = 32;
    __shared__ float sA[BK][BM + 4];   // sA[k][m] = A[bm+m][k0+k]
    __shared__ float sB[BK][BN + 4];   // sB[k][n] = W[k0+k][bn+n]
    int t = threadIdx.x;
    int bm = blockIdx.y * BM, bn = blockIdx.x * BN;
    int tm = t & 31, tn = t >> 5;      // rows tm*4.., cols tn*4..
    float acc[4][4] = {{0.f}};
    for (int k0 = 0; k0 < K; k0 += BK) {
#pragma unroll
        for (int i = 0; i < 4; ++i) {
            int q = t + i * 256;               // [0,1024)
            int m = q >> 3, kq = q & 7;        // m in [0,128), k4 = kq*4
            float4 a = *(const float4*)&A[(size_t)(bm + m) * lda + k0 + kq * 4];
            sA[kq * 4 + 0][m] = a.x;
            sA[kq * 4 + 1][m] = a.y;
            sA[kq * 4 + 2][m] = a.z;
            sA[kq * 4 + 3][m] = a.w;
        }
        {
            int n4 = t & 7, k = t >> 3;        // k in [0,32)
            float4 bv = *(const float4*)&W[(size_t)(k0 + k) * N + bn + n4 * 4];
            *(float4*)&sB[k][n4 * 4] = bv;
        }
        __syncthreads();
#pragma unroll
        for (int k = 0; k < BK; ++k) {
            float4 a4 = *(const float4*)&sA[k][tm * 4];
            float4 b4 = *(const float4*)&sB[k][tn * 4];
            float av[4] = {a4.x, a4.y, a4.z, a4.w};
            float bv[4] = {b4.x, b4.y, b4.z, b4.w};
#pragma unroll
            for (int i = 0; i < 4; ++i)
#pragma unroll
                for (int j = 0; j < 4; ++j)
                    acc[i][j] += av[i] * bv[j];
        }
        __syncthreads();
    }
    float4 bb = *(const float4*)&bias[bn + tn * 4];
    float bvv[4] = {bb.x, bb.y, bb.z, bb.w};
#pragma unroll
    for (int i = 0; i < 4; ++i) {
        float4 o;
        o.x = acc[i][0] + bvv[0];
        o.y = acc[i][1] + bvv[1];
        o.z = acc[i][2] + bvv[2];
        o.w = acc[i][3] + bvv[3];
        *(float4*)&C[(size_t)(bm + tm * 4 + i) * N + bn + tn * 4] = o;
    }
}

// ---------------- conv_layer act (oc=32): center + max_n(theta*support) summed over S ----
__global__ void act32_kernel(const float* __restrict__ nd, const int* __restrict__ idx,
                             const float* __restrict__ fout, const float* __restrict__ dirs,
                             float* __restrict__ fm, int Vv, int Cstr, int coff, int dorelu)
{
    __shared__ float snd[NS * 3];
    __shared__ int sidx[NS];
    __shared__ float sm[128];
    int b = blockIdx.y, v = blockIdx.x, t = threadIdx.x;
    size_t row = (size_t)b * Vv + v;
    if (t < NS * 3) snd[t] = nd[row * NS * 3 + t];
    if (t < NS) sidx[t] = idx[row * NS + t];
    __syncthreads();
    float w0 = dirs[t], w1 = dirs[128 + t], w2 = dirs[256 + t];
    float nn = sqrtf(w0 * w0 + w1 * w1 + w2 * w2);
    float mm = fmaxf(nn, 1e-12f);
    w0 /= mm; w1 /= mm; w2 /= mm;
    float mx = -INFINITY;
    for (int n = 0; n < NS; ++n) {
        float th = fmaxf(snd[n * 3] * w0 + snd[n * 3 + 1] * w1 + snd[n * 3 + 2] * w2, 0.0f);
        float sup = fout[((size_t)b * Vv + sidx[n]) * 160 + 32 + t];
        mx = fmaxf(mx, th * sup);
    }
    sm[t] = mx;
    __syncthreads();
    if (t < 32) {
        float act = ((sm[t] + sm[32 + t]) + sm[64 + t]) + sm[96 + t];
        float o = fout[row * 160 + t] + act;           // center + act
        if (dorelu) o = fmaxf(o, 0.0f);
        fm[row * Cstr + coff + t] = o;
    }
}

// ---------------- pool: gather-max over first 4 neighbors at permuted rows ----------------
__global__ void pool_kernel(const float* __restrict__ fmin, const int* __restrict__ idxp,
                            const int* __restrict__ perm, const float* __restrict__ vin,
                            float* __restrict__ fmout, float* __restrict__ vout,
                            int Vin, int Vout, int Cin, int Cout)
{
    int b = blockIdx.y, nv = blockIdx.x, t = threadIdx.x;
    int pv = perm[nv];
    size_t inrow = (size_t)b * Vin + pv;
    const int* ir = idxp + inrow * NS;   // radius/pointset identical -> first 4 of 32-idx
    int j0 = ir[0], j1 = ir[1], j2 = ir[2], j3 = ir[3];
    if (t < Cin) {
        const float* base = fmin + (size_t)b * Vin * Cin;
        float m = base[(size_t)j0 * Cin + t];
        m = fmaxf(m, base[(size_t)j1 * Cin + t]);
        m = fmaxf(m, base[(size_t)j2 * Cin + t]);
        m = fmaxf(m, base[(size_t)j3 * Cin + t]);
        fmout[((size_t)b * Vout + nv) * Cout + t] = m;
    }
    if (t == 0) {
        vout[((size_t)b * Vout + nv) * 3 + 0] = vin[inrow * 3 + 0];
        vout[((size_t)b * Vout + nv) * 3 + 1] = vin[inrow * 3 + 1];
        vout[((size_t)b * Vout + nv) * 3 + 2] = vin[inrow * 3 + 2];
    }
}

// ---------------- layer-8 act (oc=1024, K=S*1024=4096) ----------------
__global__ void act8_kernel(const float* __restrict__ nd, const int* __restrict__ idx,
                            const float* __restrict__ fout8, const float* __restrict__ dir8,
                            float* __restrict__ fm8)
{
    __shared__ float sdx[4096], sdy[4096], sdz[4096];   // 48 KB normalized dirs
    __shared__ float snd[NS * 3];
    __shared__ int sidx[NS];
    int b = blockIdx.y, v = blockIdx.x, t = threadIdx.x;
    for (int c = t; c < 4096; c += 256) {
        float w0 = dir8[c], w1 = dir8[4096 + c], w2 = dir8[8192 + c];
        float nn = sqrtf(w0 * w0 + w1 * w1 + w2 * w2);
        float mm = fmaxf(nn, 1e-12f);
        sdx[c] = w0 / mm; sdy[c] = w1 / mm; sdz[c] = w2 / mm;
    }
    size_t row = (size_t)b * 256 + v;
    if (t < NS * 3) snd[t] = nd[row * NS * 3 + t];
    if (t < NS) sidx[t] = idx[row * NS + t];
    __syncthreads();
    float mx[16];
#pragma unroll
    for (int u = 0; u < 16; ++u) mx[u] = -INFINITY;
    for (int n = 0; n < NS; ++n) {
        float a0 = snd[n * 3], a1 = snd[n * 3 + 1], a2 = snd[n * 3 + 2];
        const float* sup = fout8 + ((size_t)b * 256 + sidx[n]) * 5120 + 1024;
#pragma unroll
        for (int u = 0; u < 16; ++u) {
            int k = t + 256 * u;
            float th = fmaxf(a0 * sdx[k] + a1 * sdy[k] + a2 * sdz[k], 0.0f);
            mx[u] = fmaxf(mx[u], th * sup[k]);
        }
    }
    const float* crow = fout8 + row * 5120;
#pragma unroll
    for (int w = 0; w < 4; ++w) {
        int c = t + 256 * w;
        float act = ((mx[w] + mx[4 + w]) + mx[8 + w]) + mx[12 + w];
        fm8[row * 1024 + c] = crow[c] + act;            // no relu on fm8
    }
}

// ---------------- global max over vertices: two-stage ----------------
// stage 1: grid (4 col-chunks, 8 v-chunks, 2 b); each block maxes 32 rows x 256 cols
__global__ void gmax_part_kernel(const float* __restrict__ fm8, float* __restrict__ part)
{
    int cc = blockIdx.x, vc = blockIdx.y, b = blockIdx.z, t = threadIdx.x;
    int c = cc * 256 + t;
    float m = -INFINITY;
#pragma unroll 8
    for (int v = vc * 32; v < vc * 32 + 32; ++v)
        m = fmaxf(m, fm8[((size_t)b * 256 + v) * 1024 + c]);
    part[((size_t)b * 8 + vc) * 1024 + c] = m;
}

// stage 2: 2048 threads, each maxes the 8 partials for its (b,c)
__global__ void gmax_final_kernel(const float* __restrict__ part, float* __restrict__ gfeat)
{
    int t = blockIdx.x * blockDim.x + threadIdx.x;  // 0..2047
    if (t >= 2048) return;
    int b = t >> 10, c = t & 1023;
    float m = -INFINITY;
#pragma unroll
    for (int vc = 0; vc < 8; ++vc)
        m = fmaxf(m, part[((size_t)b * 8 + vc) * 1024 + c]);
    gfeat[t] = m;
}

// ---------------- classifier head, stage 1: h = relu(BN(gfeat @ cw1 + cb1)) ----------------
// grid (16 col-chunks, 2 b); 256 threads = 16 k-groups x 16 cols; each thread sums 64 k's
__global__ void head1_kernel(const float* __restrict__ gfeat,
                             const float* __restrict__ cw1, const float* __restrict__ cb1,
                             const float* __restrict__ bg, const float* __restrict__ bbv,
                             float* __restrict__ h)
{
    __shared__ float sg[1024];
    __shared__ float sp[16][17];
    int b = blockIdx.y, c0 = blockIdx.x * 16, t = threadIdx.x;
    for (int i = t; i < 1024; i += 256) sg[i] = gfeat[b * 1024 + i];
    __syncthreads();
    int kg = t >> 4, cl = t & 15;
    float acc = 0.f;
#pragma unroll 8
    for (int i = 0; i < 64; ++i) {
        int k = kg * 64 + i;
        acc += sg[k] * cw1[k * 256 + c0 + cl];
    }
    sp[kg][cl] = acc;
    __syncthreads();
    if (t < 16) {
        float a = 0.f;
#pragma unroll
        for (int g = 0; g < 16; ++g) a += sp[g][t];
        int c = c0 + t;
        float hv = a + cb1[c];
        const float s = sqrtf((float)(1.0 + 1e-5));
        hv = hv / s * bg[c] + bbv[c];
        h[b * 256 + c] = fmaxf(hv, 0.0f);
    }
}

// ---------------- classifier head, stage 2: out = h @ cw2 + cb2 ----------------
__global__ void head2_kernel(const float* __restrict__ h,
                             const float* __restrict__ cw2, const float* __restrict__ cb2,
                             float* __restrict__ out)
{
    __shared__ float sh[256];
    int b = blockIdx.x, t = threadIdx.x;
    sh[t] = h[b * 256 + t];
    __syncthreads();
    if (t < 40) {
        float a = 0.f;
        for (int i = 0; i < 256; ++i) a += sh[i] * cw2[i * 40 + t];
        out[b * 40 + t] = a + cb2[t];
    }
}

// ==================================================================
extern "C" void kernel_launch(void* const* d_in, const int* in_sizes, int n_in,
                              void* d_out, int out_size, void* d_ws, size_t ws_size,
                              hipStream_t stream)
{
    (void)in_sizes; (void)n_in; (void)out_size; (void)ws_size;
    const float* vertices = (const float*)d_in[0];
    const float* d0 = (const float*)d_in[1];
    const float *w[9], *bw[9], *dir[9];
    for (int i = 1; i <= 8; ++i) {
        w[i]   = (const float*)d_in[2 + (i - 1) * 3];
        bw[i]  = (const float*)d_in[3 + (i - 1) * 3];
        dir[i] = (const float*)d_in[4 + (i - 1) * 3];
    }
    const float* cw1 = (const float*)d_in[26];
    const float* cb1 = (const float*)d_in[27];
    const float* bg  = (const float*)d_in[28];
    const float* bbv = (const float*)d_in[29];
    const float* cw2 = (const float*)d_in[30];
    const float* cb2 = (const float*)d_in[31];
    float* out = (float*)d_out;

    char* ws = (char*)d_ws;
    size_t off = 0;
    auto take = [&](size_t bytes) -> char* {
        char* p = ws + off;
        off = (off + bytes + 255) & ~(size_t)255;
        return p;
    };
    uint32_t* keys1 = (uint32_t*)take(4096 * 4);
    int* valA = (int*)take(4096 * 4);
    int* valB = (int*)take(4096 * 4);
    uint32_t* keys2 = (uint32_t*)take(1024 * 4);
    int* v2A = (int*)take(1024 * 4);
    int* v2B = (int*)take(1024 * 4);
    int*   idx1 = (int*)take((size_t)2 * 4096 * NS * 4);
    float* nd1  = (float*)take((size_t)2 * 4096 * NS * 3 * 4);
    float* fmA  = (float*)take((size_t)2 * 4096 * 96 * 4);
    float* vtxB = (float*)take((size_t)2 * 1024 * 3 * 4);
    int*   idx2 = (int*)take((size_t)2 * 1024 * NS * 4);
    float* nd2  = (float*)take((size_t)2 * 1024 * NS * 3 * 4);
    float* fmB  = (float*)take((size_t)2 * 1024 * 192 * 4);
    float* vtxC = (float*)take((size_t)2 * 256 * 3 * 4);
    int*   idx3 = (int*)take((size_t)2 * 256 * NS * 4);
    float* nd3  = (float*)take((size_t)2 * 256 * NS * 3 * 4);
    float* fmC  = (float*)take((size_t)2 * 256 * 256 * 4);
    float* fm8  = (float*)take((size_t)2 * 256 * 1024 * 4);
    float* gpart = (float*)take((size_t)2 * 8 * 1024 * 4);
    float* gfeat = (float*)take(2 * 1024 * 4);
    float* hbuf  = (float*)take(2 * 256 * 4);
    float* fout = (float*)take((size_t)512 * 5120 * 4);  // shared by all fout layers

    // permutations (jax.random.permutation, partitionable threefry;
    // 2 sort rounds for n=4096, 1 for n=1024)
    perm_genkeys<<<16, 256, 0, stream>>>(keys1, valA, 1u, 0, 4096, 1);
    perm_rank<4096><<<1024, 256, 0, stream>>>(keys1, valA, valB);
    perm_genkeys<<<16, 256, 0, stream>>>(keys1, valA, 1u, 1, 4096, 0);
    perm_rank<4096><<<1024, 256, 0, stream>>>(keys1, valB, valA);   // perm1 = valA[:1024]
    perm_genkeys<<<4, 256, 0, stream>>>(keys2, v2A, 2u, 0, 1024, 1);
    perm_rank<1024><<<256, 256, 0, stream>>>(keys2, v2A, v2B);      // perm2 = v2B[:256]

    const float r2a = (float)(0.2 * 0.2), r2b = (float)(0.4 * 0.4), r2c = (float)(0.6 * 0.6);

    // ---- stage 1: V=4096 ----
    qbp_wave_kernel<<<dim3(1024, 2), 256, 0, stream>>>(vertices, 4096, r2a, idx1, nd1);
    conv_surface_kernel<<<dim3(4096, 2), 128, 0, stream>>>(nd1, d0, fmA, 4096, 96, 0);
    gemm_kernel<<<dim3(5, 64), 256, 0, stream>>>(fmA, w[1], bw[1], fout, 32, 160, 96);
    act32_kernel<<<dim3(4096, 2), 128, 0, stream>>>(nd1, idx1, fout, dir[1], fmA, 4096, 96, 32, 1);
    gemm_kernel<<<dim3(5, 64), 256, 0, stream>>>(fmA, w[2], bw[2], fout, 64, 160, 96);
    act32_kernel<<<dim3(4096, 2), 128, 0, stream>>>(nd1, idx1, fout, dir[2], fmA, 4096, 96, 64, 1);
    pool_kernel<<<dim3(1024, 2), 128, 0, stream>>>(fmA, idx1, valA, vertices, fmB, vtxB, 4096, 1024, 96, 192);

    // ---- stage 2: V=1024 ----
    qbp_wave_kernel<<<dim3(256, 2), 256, 0, stream>>>(vtxB, 1024, r2b, idx2, nd2);
    gemm_kernel<<<dim3(5, 16), 256, 0, stream>>>(fmB, w[3], bw[3], fout, 96, 160, 192);
    act32_kernel<<<dim3(1024, 2), 128, 0, stream>>>(nd2, idx2, fout, dir[3], fmB, 1024, 192, 96, 1);
    gemm_kernel<<<dim3(5, 16), 256, 0, stream>>>(fmB, w[4], bw[4], fout, 128, 160, 192);
    act32_kernel<<<dim3(1024, 2), 128, 0, stream>>>(nd2, idx2, fout, dir[4], fmB, 1024, 192, 128, 1);
    gemm_kernel<<<dim3(5, 16), 256, 0, stream>>>(fmB, w[5], bw[5], fout, 160, 160, 192);
    act32_kernel<<<dim3(1024, 2), 128, 0, stream>>>(nd2, idx2, fout, dir[5], fmB, 1024, 192, 160, 1);
    pool_kernel<<<dim3(256, 2), 256, 0, stream>>>(fmB, idx2, v2B, vtxB, fmC, vtxC, 1024, 256, 192, 256);

    // ---- stage 3: V=256 ----
    qbp_wave_kernel<<<dim3(64, 2), 256, 0, stream>>>(vtxC, 256, r2c, idx3, nd3);
    gemm_kernel<<<dim3(5, 4), 256, 0, stream>>>(fmC, w[6], bw[6], fout, 192, 160, 256);
    act32_kernel<<<dim3(256, 2), 128, 0, stream>>>(nd3, idx3, fout, dir[6], fmC, 256, 256, 192, 1);
    gemm_kernel<<<dim3(5, 4), 256, 0, stream>>>(fmC, w[7], bw[7], fout, 224, 160, 256);
    act32_kernel<<<dim3(256, 2), 128, 0, stream>>>(nd3, idx3, fout, dir[7], fmC, 256, 256, 224, 1);

    // ---- layer 8 + head ----
    gemm_kernel<<<dim3(160, 4), 256, 0, stream>>>(fmC, w[8], bw[8], fout, 256, 5120, 256);
    act8_kernel<<<dim3(256, 2), 256, 0, stream>>>(nd3, idx3, fout, dir[8], fm8);
    gmax_part_kernel<<<dim3(4, 8, 2), 256, 0, stream>>>(fm8, gpart);
    gmax_final_kernel<<<8, 256, 0, stream>>>(gpart, gfeat);
    head1_kernel<<<dim3(16, 2), 256, 0, stream>>>(gfeat, cw1, cb1, bg, bbv, hbuf);
    head2_kernel<<<2, 256, 0, stream>>>(hbuf, cw2, cb2, out);
}